// Round 16
// baseline (586.308 us; speedup 1.0000x reference)
//
#include <hip/hip_runtime.h>

// GeometricModalityFusion on MI355X — round 16: r7 schedule + B-operand direct
// from L2 (no LDS staging for the weight matrix; A-only 64KB LDS dbuf).
// f32 in/out; bf16 16x16x32 MFMA. B=8, S=2048, D=1024, H=16 (hd=64), M=3.

typedef __attribute__((ext_vector_type(8))) short bf16x8;
typedef __attribute__((ext_vector_type(4))) float f32x4;
typedef __attribute__((ext_vector_type(8))) unsigned short u16x8;

__device__ __forceinline__ float b2f(unsigned short u) {
    return __uint_as_float(((unsigned int)u) << 16);
}
__device__ __forceinline__ unsigned short f2b(float f) {
    unsigned int x = __float_as_uint(f);
    x += 0x7fffu + ((x >> 16) & 1u);   // RNE
    return (unsigned short)(x >> 16);
}
__device__ __forceinline__ void gl_lds16(const unsigned short* g, const unsigned short* l) {
    __builtin_amdgcn_global_load_lds(
        (const __attribute__((address_space(1))) unsigned int*)g,
        (__attribute__((address_space(3))) unsigned int*)(unsigned short*)l, 16, 0, 0);
}

// ---------------------------------------------------------------------------
// merged weight transpose+convert: 7 matrices f32 [K][1024] -> bf16 [1024][K]
// ---------------------------------------------------------------------------
struct WtArgs {
    const float* src[7];
    unsigned short* dst[7];
    int K[7];
    int cum[8];
};

__global__ __launch_bounds__(256) void wtrans_all(WtArgs a)
{
    __shared__ float t[32][33];
    const int bid = blockIdx.x;
    int m = 0;
    while (bid >= a.cum[m + 1]) ++m;
    const int local = bid - a.cum[m];
    const int K = a.K[m];
    const int kb = K >> 5;
    const int k0 = (local % kb) * 32;
    const int n0 = (local / kb) * 32;
    const float* in = a.src[m];
    unsigned short* out = a.dst[m];
    const int N = 1024;

    const int tx = threadIdx.x & 31, ty = threadIdx.x >> 5;
#pragma unroll
    for (int r = ty; r < 32; r += 8)
        t[r][tx] = in[(size_t)(k0 + r) * N + n0 + tx];
    __syncthreads();
#pragma unroll
    for (int r = ty; r < 32; r += 8)
        out[(size_t)(n0 + r) * K + k0 + tx] = f2b(t[tx][r]);
}

// merged f32 -> bf16 convert over 3 source segments into one contiguous dst
struct CvtArgs {
    const float* s0; const float* s1; const float* s2;
    long c0, c1, ntot;
};

__global__ __launch_bounds__(256) void cvt_all(CvtArgs a, unsigned short* __restrict__ dst)
{
    for (long i = (long)blockIdx.x * 256 + threadIdx.x; i < a.ntot; i += (long)gridDim.x * 256) {
        const float* src; long off;
        if (i < a.c0)      { src = a.s0; off = i; }
        else if (i < a.c1) { src = a.s1; off = i - a.c0; }
        else               { src = a.s2; off = i - a.c1; }
        const float4 v0 = *reinterpret_cast<const float4*>(src + off * 8);
        const float4 v1 = *reinterpret_cast<const float4*>(src + off * 8 + 4);
        u16x8 w;
        w[0]=f2b(v0.x); w[1]=f2b(v0.y); w[2]=f2b(v0.z); w[3]=f2b(v0.w);
        w[4]=f2b(v1.x); w[5]=f2b(v1.y); w[6]=f2b(v1.z); w[7]=f2b(v1.w);
        *reinterpret_cast<u16x8*>(dst + i * 8) = w;
    }
}

// ---------------------------------------------------------------------------
// 256x256 GEMM, r7 schedule, B-operand DIRECT from global (L2-resident weight
// matrix — no LDS staging for B). LDS holds only A: 2 dbuf x 32KB.
// 512 threads = 8 waves (2M x 4N); per-wave 128x64 (acc[8][4]); BK=64.
// Per tile: ph0 {MFMA Q00(bfA) | stage A(t+1) 4x gl_lds} ;
//           ph1 {MFMA Q02(bfB) | ds_read af47(cur)} ;
//           ph2 {MFMA Q42(bfB) | global-load bfB <- t+1} ;
//           ph3 {MFMA Q40(bfA) | global-load bfA <- t+1} ;
//           vmcnt(8) [drains only the 4 A-DMAs; 8 B-loads ride through];
//           BAR; ds_read af03(nb).
// T2 swizzle on A only; T1 XCD swizzle; T5 setprio.
// ---------------------------------------------------------------------------
template<int CF32>
__global__ __launch_bounds__(512, 2) void gemm_bd(
    const unsigned short* __restrict__ A, const unsigned short* __restrict__ Bt,
    const float* __restrict__ bias, void* __restrict__ Cout,
    int Ndim, int Kdim, int a_rpb, int a_bs, int c_rpb, int c_bs, int nt)
{
    extern __shared__ __align__(16) unsigned short lds[];   // A dbuf: 2 x 16384 elems

    const int tid  = threadIdx.x;
    const int lane = tid & 63;
    const int w    = tid >> 6;
    const int wm = w >> 2, wn = w & 3;
    const int lr = lane & 15, lk = lane >> 4;

    const int ncol = Ndim >> 8;
    const int cpx  = gridDim.x >> 3;
    const int wgid = (blockIdx.x & 7) * cpx + (blockIdx.x >> 3);
    const int m0 = (wgid / ncol) << 8;
    const int n0 = (wgid % ncol) << 8;

    // A staging: thread covers row srow of each 64-row region j, 16B slot
    // pre-swizzled by row&7 on the GLOBAL side; LDS dest linear.
    const int srow  = tid >> 3;
    const int gslot = (tid & 7) ^ (srow & 7);
    const int gr0   = m0 + srow;
    const size_t asrc0 = ((size_t)((gr0 / a_rpb) * a_bs + (gr0 % a_rpb))) * Kdim + gslot * 8;
    const size_t rstep = (size_t)64 * Kdim;
    const int sdst = (w << 9);   // wave-uniform LDS base (HW adds lane*16B)

#define STAGE_A(doff, j, tt) gl_lds16(A + asrc0 + (size_t)(j)*rstep + (size_t)(tt)*64, \
                                      lds + (doff) + (j)*4096 + sdst)

    // A read offsets (XOR swizzle matching write side)
    const int sel0 = ((lk)     ^ (lr & 7)) * 8;
    const int sel1 = ((lk + 4) ^ (lr & 7)) * 8;
    const int arow = (wm * 128 + lr) * 64;

    // B direct per-lane fragment base pointers: col-block c (0..3) of this
    // wave's 64-col stripe; element offset within row = k0 + lk*8 (+32).
    const unsigned short* bbase[4];
#pragma unroll
    for (int c = 0; c < 4; ++c)
        bbase[c] = Bt + (size_t)(n0 + wn * 64 + c * 16 + lr) * Kdim + lk * 8;

#define LDV(off) (*reinterpret_cast<const bf16x8*>(lds + (off)))
#define LDG(p)   (*reinterpret_cast<const bf16x8*>(p))

    f32x4 acc[8][4];
    const f32x4 zero = {0.f, 0.f, 0.f, 0.f};
#pragma unroll
    for (int a = 0; a < 8; ++a)
#pragma unroll
        for (int b = 0; b < 4; ++b) acc[a][b] = zero;

    bf16x8 af[4][2], bfA[2][2], bfB[2][2];

#define READ_AF(base, roff) \
    _Pragma("unroll") \
    for (int a = 0; a < 4; ++a) { \
        af[a][0] = LDV((base) + arow + ((roff) + a) * 1024 + sel0); \
        af[a][1] = LDV((base) + arow + ((roff) + a) * 1024 + sel1); \
    }
#define LOADB_A(tt) \
    _Pragma("unroll") \
    for (int b = 0; b < 2; ++b) { \
        bfA[b][0] = LDG(bbase[b] + (tt) * 64); \
        bfA[b][1] = LDG(bbase[b] + (tt) * 64 + 32); \
    }
#define LOADB_B(tt) \
    _Pragma("unroll") \
    for (int b = 0; b < 2; ++b) { \
        bfB[b][0] = LDG(bbase[2 + b] + (tt) * 64); \
        bfB[b][1] = LDG(bbase[2 + b] + (tt) * 64 + 32); \
    }

#define MFMA_Q(RA, CB, BF) \
    _Pragma("unroll") \
    for (int a = 0; a < 4; ++a) { \
        _Pragma("unroll") \
        for (int b = 0; b < 2; ++b) { \
            acc[RA+a][CB+b] = __builtin_amdgcn_mfma_f32_16x16x32_bf16(af[a][0], BF[b][0], acc[RA+a][CB+b], 0, 0, 0); \
            acc[RA+a][CB+b] = __builtin_amdgcn_mfma_f32_16x16x32_bf16(af[a][1], BF[b][1], acc[RA+a][CB+b], 0, 0, 0); \
        } \
    }

    // prologue: stage A tile 0; load B frags tile 0; drain; barrier; read af03
#pragma unroll
    for (int j = 0; j < 4; ++j) STAGE_A(0, j, 0);
    LOADB_A(0);
    LOADB_B(0);
    asm volatile("s_waitcnt vmcnt(0)" ::: "memory");
    __builtin_amdgcn_s_barrier();
    READ_AF(0, 0);

    for (int t = 0; t < nt; ++t) {
        const int cur = (t & 1) << 14;
        const int nb  = ((t + 1) & 1) << 14;
        const bool pf = (t + 1) < nt;

        // ph0: MFMA Q00 (af03 x bfA) ; stage A(t+1)
        __builtin_amdgcn_s_setprio(1);
        MFMA_Q(0, 0, bfA);
        __builtin_amdgcn_s_setprio(0);
        if (pf) {
            STAGE_A(nb, 0, t+1); STAGE_A(nb, 1, t+1);
            STAGE_A(nb, 2, t+1); STAGE_A(nb, 3, t+1);
        }

        // ph1: MFMA Q02 (af03 x bfB) ; ds_read af47(cur)
        __builtin_amdgcn_s_setprio(1);
        MFMA_Q(0, 2, bfB);
        __builtin_amdgcn_s_setprio(0);
        READ_AF(cur, 4);

        // ph2: MFMA Q42 (af47 x bfB) ; then refill bfB from t+1 (global, L2-hot)
        __builtin_amdgcn_s_setprio(1);
        MFMA_Q(4, 2, bfB);
        __builtin_amdgcn_s_setprio(0);
        if (pf) LOADB_B(t + 1);

        // ph3: MFMA Q40 (af47 x bfA) ; then refill bfA from t+1
        __builtin_amdgcn_s_setprio(1);
        MFMA_Q(4, 0, bfA);
        __builtin_amdgcn_s_setprio(0);
        if (pf) LOADB_A(t + 1);

        // boundary: drain only the 4 A-DMAs (oldest); 8 B-loads stay in flight
        if (pf) {
            asm volatile("s_waitcnt vmcnt(8)" ::: "memory");
        } else {
            asm volatile("s_waitcnt vmcnt(0)" ::: "memory");
        }
        __builtin_amdgcn_s_barrier();
        if (pf) READ_AF(nb, 0);
    }

    // epilogue: C/D layout col=lane&15, row=(lane>>4)*4+r; bias hoisted
    const int grow0 = m0 + wm * 128;
    const int crow0 = (grow0 / c_rpb) * c_bs + (grow0 % c_rpb);
    float bv[4];
#pragma unroll
    for (int b = 0; b < 4; ++b) bv[b] = bias[n0 + wn * 64 + b * 16 + lr];
#pragma unroll
    for (int a = 0; a < 8; ++a) {
#pragma unroll
        for (int b = 0; b < 4; ++b) {
            const int gcol = n0 + wn * 64 + b * 16 + lr;
#pragma unroll
            for (int r = 0; r < 4; ++r) {
                const int crow = crow0 + a * 16 + lk * 4 + r;
                if constexpr (CF32) {
                    ((float*)Cout)[(size_t)crow * Ndim + gcol] = acc[a][b][r] + bv[b];
                } else {
                    ((unsigned short*)Cout)[(size_t)crow * Ndim + gcol] = f2b(acc[a][b][r] + bv[b]);
                }
            }
        }
    }
#undef STAGE_A
#undef LDV
#undef LDG
#undef READ_AF
#undef LOADB_A
#undef LOADB_B
#undef MFMA_Q
}

// ---------------------------------------------------------------------------
// Combined scores (blocks 0..4095) + gram partials (blocks 4096..4607).
// ---------------------------------------------------------------------------
__global__ __launch_bounds__(256) void scores_gram_kernel(
    const unsigned short* __restrict__ Q, const unsigned short* __restrict__ Kb,
    const float* __restrict__ temp, float* __restrict__ attn,
    const unsigned short* __restrict__ feats, float* __restrict__ gpart)
{
    __shared__ float red[4][9];
    if (blockIdx.x < 4096) {
        const int lane = threadIdx.x & 63;
        const int w  = blockIdx.x * 4 + (threadIdx.x >> 6);
        const int b  = w >> 11;
        const int s  = w & 2047;
        const float t = fabsf(temp[0]);
        const float inv = 1.f / (8.f * t);
        const size_t qbase = (((size_t)w) << 10) + lane * 8;
        const u16x8 qv0 = *reinterpret_cast<const u16x8*>(Q + qbase);
        const u16x8 qv1 = *reinterpret_cast<const u16x8*>(Q + qbase + 512);
        float sc0[3], sc1[3];
#pragma unroll
        for (int m = 0; m < 3; ++m) {
            const size_t koff = ((((size_t)(b*3 + m) << 11) + s) << 10) + lane * 8;
            const u16x8 kv0 = *reinterpret_cast<const u16x8*>(Kb + koff);
            const u16x8 kv1 = *reinterpret_cast<const u16x8*>(Kb + koff + 512);
            float p0 = 0.f, p1 = 0.f;
#pragma unroll
            for (int j = 0; j < 8; ++j) {
                p0 = fmaf(b2f(qv0[j]), b2f(kv0[j]), p0);
                p1 = fmaf(b2f(qv1[j]), b2f(kv1[j]), p1);
            }
            p0 += __shfl_xor(p0, 1); p0 += __shfl_xor(p0, 2); p0 += __shfl_xor(p0, 4);
            p1 += __shfl_xor(p1, 1); p1 += __shfl_xor(p1, 2); p1 += __shfl_xor(p1, 4);
            sc0[m] = p0 * inv;
            sc1[m] = p1 * inv;
        }
        const float mx0 = fmaxf(sc0[0], fmaxf(sc0[1], sc0[2]));
        const float a0 = expf(sc0[0]-mx0), a1 = expf(sc0[1]-mx0), a2 = expf(sc0[2]-mx0);
        const float is0 = 1.f / (a0 + a1 + a2);
        const float mx1 = fmaxf(sc1[0], fmaxf(sc1[1], sc1[2]));
        const float c0 = expf(sc1[0]-mx1), c1 = expf(sc1[1]-mx1), c2 = expf(sc1[2]-mx1);
        const float is1 = 1.f / (c0 + c1 + c2);
        if ((lane & 7) == 0) {
            const int h0 = lane >> 3;
            const size_t b0 = ((size_t)w * 16 + h0) * 3;
            const size_t b1 = ((size_t)w * 16 + 8 + h0) * 3;
            attn[b0+0] = a0 * is0; attn[b0+1] = a1 * is0; attn[b0+2] = a2 * is0;
            attn[b1+0] = c0 * is1; attn[b1+1] = c1 * is1; attn[b1+2] = c2 * is1;
        }
        return;
    }

    const int gb    = blockIdx.x - 4096;
    const int b     = gb >> 6;
    const int chunk = gb & 63;
    const int wave  = threadIdx.x >> 6;
    const int lane  = threadIdx.x & 63;
    float acc[9];
#pragma unroll
    for (int i = 0; i < 9; ++i) acc[i] = 0.f;
    const int s_base = chunk * 32 + wave * 8;
    const size_t bbase = ((size_t)(b*3)) << 21;
    for (int ti = 0; ti < 8; ++ti) {
        const size_t rowoff = ((size_t)(s_base + ti)) << 10;
        float g[6] = {0.f,0.f,0.f,0.f,0.f,0.f};
#pragma unroll
        for (int half = 0; half < 2; ++half) {
            const int d = (half << 9) + (lane << 3);
            u16x8 v0 = *(const u16x8*)(feats + bbase + rowoff + d);
            u16x8 v1 = *(const u16x8*)(feats + bbase + ((size_t)1<<21) + rowoff + d);
            u16x8 v2 = *(const u16x8*)(feats + bbase + ((size_t)2<<21) + rowoff + d);
#pragma unroll
            for (int j = 0; j < 8; ++j) {
                float x0 = b2f(v0[j]), x1 = b2f(v1[j]), x2 = b2f(v2[j]);
                g[0] = fmaf(x0,x0,g[0]); g[1] = fmaf(x0,x1,g[1]); g[2] = fmaf(x0,x2,g[2]);
                g[3] = fmaf(x1,x1,g[3]); g[4] = fmaf(x1,x2,g[4]); g[5] = fmaf(x2,x2,g[5]);
            }
        }
#pragma unroll
        for (int i = 0; i < 6; ++i) {
#pragma unroll
            for (int o = 32; o > 0; o >>= 1) g[i] += __shfl_xor(g[i], o);
        }
        const float n0 = fmaxf(sqrtf(g[0]), 1e-12f);
        const float n1 = fmaxf(sqrtf(g[3]), 1e-12f);
        const float n2 = fmaxf(sqrtf(g[5]), 1e-12f);
        acc[0]+=g[0]; acc[1]+=g[1]; acc[2]+=g[2]; acc[3]+=g[3]; acc[4]+=g[4]; acc[5]+=g[5];
        acc[6]+=g[1]/(n0*n1); acc[7]+=g[2]/(n0*n2); acc[8]+=g[4]/(n1*n2);
    }
    if (lane == 0) {
#pragma unroll
        for (int i = 0; i < 9; ++i) red[wave][i] = acc[i];
    }
    __syncthreads();
    if (threadIdx.x == 0) {
#pragma unroll
        for (int i = 0; i < 9; ++i)
            gpart[gb * 9 + i] = red[0][i] + red[1][i] + red[2][i] + red[3][i];
    }
}

// per-batch scalar weights: angular (aw) + cayley (cw) + fusion softmax (fw)
__global__ void weights_kernel(const float* __restrict__ gpart,
                               const float* __restrict__ temp,
                               const float* __restrict__ attnw,
                               float* __restrict__ coef)
{
    const int b = threadIdx.x;
    if (b >= 8) return;
    const float t = fabsf(temp[0]);

    float a0 = attnw[0], a1 = attnw[1], a2 = attnw[2];
    float amx = fmaxf(a0, fmaxf(a1, a2));
    float fe0 = expf(a0-amx), fe1 = expf(a1-amx), fe2 = expf(a2-amx);
    float fs = fe0 + fe1 + fe2;
    float fw0 = fe0/fs, fw1 = fe1/fs, fw2 = fe2/fs;

    float g[9];
#pragma unroll
    for (int i = 0; i < 9; ++i) {
        float ssum = 0.f;
        for (int c = 0; c < 64; ++c) ssum += gpart[(b*64 + c)*9 + i];
        g[i] = ssum;
    }
    const float G[3][3] = {{g[0],g[1],g[2]},{g[1],g[3],g[4]},{g[2],g[4],g[5]}};

    const float c01 = g[6] / 2048.f, c02 = g[7] / 2048.f, c12 = g[8] / 2048.f;
    const float lo = -1.f + 1e-7f, hi = 1.f - 1e-7f;
    const float ang01 = acosf(fminf(fmaxf(c01, lo), hi));
    const float ang02 = acosf(fminf(fmaxf(c02, lo), hi));
    const float ang12 = acosf(fminf(fmaxf(c12, lo), hi));
    const float e01 = expf(-ang01/t), e02 = expf(-ang02/t), e12 = expf(-ang12/t);
    const float l0 = e01*(-0.75f) + e02*(0.75f);
    const float l1 = e01*(1.0f)   + e12*(0.75f);
    const float l2 = e02*(1.0f)   + e12*(-0.75f);
    const float lm = fmaxf(l0, fmaxf(l1, l2));
    const float ae0 = expf(l0-lm), ae1 = expf(l1-lm), ae2 = expf(l2-lm);
    const float as = ae0 + ae1 + ae2;
    const float aw[3] = {ae0/as, ae1/as, ae2/as};

    float vol[3];
#pragma unroll
    for (int i = 0; i < 3; ++i) {
        float Ac[3][3] = {{0.f,0.f,0.f},{0.f,0.f,0.f},{0.f,0.f,0.f}};
        Ac[0][i] = 1.f;
        Ac[1][i] = 0.70710678f; Ac[1][(i+1)%3] += 0.70710678f;
        Ac[2][(i+2)%3] = 1.f;
        float Gi[3][3];
        for (int p = 0; p < 3; ++p)
            for (int q = 0; q < 3; ++q) {
                float ssum = 0.f;
                for (int k = 0; k < 3; ++k)
                    for (int l = 0; l < 3; ++l)
                        ssum += Ac[p][k] * G[k][l] * Ac[q][l];
                Gi[p][q] = ssum;
            }
        float ds = 0.f;
        for (int p = 0; p < 3; ++p)
            for (int q = 0; q < 3; ++q)
                ds += Gi[p][p] + Gi[q][q] - 2.f*Gi[p][q];
        vol[i] = ds / 9.f;
    }
    const float lv0 = vol[0]/t, lv1 = vol[1]/t, lv2 = vol[2]/t;
    const float vm = fmaxf(lv0, fmaxf(lv1, lv2));
    const float ce0 = expf(lv0-vm), ce1 = expf(lv1-vm), ce2 = expf(lv2-vm);
    const float cs = ce0 + ce1 + ce2;
    const float cw[3] = {ce0/cs, ce1/cs, ce2/cs};

    coef[b*4+0] = fw1*aw[0] + fw2*cw[0];
    coef[b*4+1] = fw1*aw[1] + fw2*cw[1];
    coef[b*4+2] = fw1*aw[2] + fw2*cw[2];
    coef[b*4+3] = fw0;
}

// ---------------------------------------------------------------------------
// Merged mha+fuse.
// ---------------------------------------------------------------------------
__global__ __launch_bounds__(256) void fusemha_kernel(
    const unsigned short* __restrict__ Vb, const unsigned short* __restrict__ feats,
    const float* __restrict__ attn, const float* __restrict__ coef,
    unsigned short* __restrict__ fused)
{
    const int lane = threadIdx.x & 63;
    const int w  = blockIdx.x * 4 + (threadIdx.x >> 6);
    const int b  = w >> 11;
    const int s  = w & 2047;
    const int h0 = lane >> 3;
    const float fw0 = coef[b*4+3];
    const float c0 = coef[b*4+0], c1 = coef[b*4+1], c2 = coef[b*4+2];
    const size_t ab0 = ((size_t)w * 16 + h0) * 3;
    const size_t ab1 = ((size_t)w * 16 + 8 + h0) * 3;
    const float a00 = fw0*attn[ab0+0], a01 = fw0*attn[ab0+1], a02 = fw0*attn[ab0+2];
    const float a10 = fw0*attn[ab1+0], a11 = fw0*attn[ab1+1], a12 = fw0*attn[ab1+2];
    const size_t base = ((((size_t)(b*3) << 11) + s) << 10) + lane * 8;
    const size_t ms = (size_t)1 << 21;
    const u16x8 v00 = *reinterpret_cast<const u16x8*>(Vb + base);
    const u16x8 v01 = *reinterpret_cast<const u16x8*>(Vb + base + ms);
    const u16x8 v02 = *reinterpret_cast<const u16x8*>(Vb + base + 2*ms);
    const u16x8 v10 = *reinterpret_cast<const u16x8*>(Vb + base + 512);
    const u16x8 v11 = *reinterpret_cast<const u16x8*>(Vb + base + ms + 512);
    const u16x8 v12 = *reinterpret_cast<const u16x8*>(Vb + base + 2*ms + 512);
    const u16x8 f00 = *reinterpret_cast<const u16x8*>(feats + base);
    const u16x8 f01 = *reinterpret_cast<const u16x8*>(feats + base + ms);
    const u16x8 f02 = *reinterpret_cast<const u16x8*>(feats + base + 2*ms);
    const u16x8 f10 = *reinterpret_cast<const u16x8*>(feats + base + 512);
    const u16x8 f11 = *reinterpret_cast<const u16x8*>(feats + base + ms + 512);
    const u16x8 f12 = *reinterpret_cast<const u16x8*>(feats + base + 2*ms + 512);
    u16x8 o0, o1;
#pragma unroll
    for (int j = 0; j < 8; ++j) {
        o0[j] = f2b(a00*b2f(v00[j]) + a01*b2f(v01[j]) + a02*b2f(v02[j])
                  + c0*b2f(f00[j]) + c1*b2f(f01[j]) + c2*b2f(f02[j]));
        o1[j] = f2b(a10*b2f(v10[j]) + a11*b2f(v11[j]) + a12*b2f(v12[j])
                  + c0*b2f(f10[j]) + c1*b2f(f11[j]) + c2*b2f(f12[j]));
    }
    const size_t qoff = (((size_t)w) << 10) + lane * 8;
    *reinterpret_cast<u16x8*>(fused + qoff) = o0;
    *reinterpret_cast<u16x8*>(fused + qoff + 512) = o1;
}

// ---------------------------------------------------------------------------
extern "C" void kernel_launch(void* const* d_in, const int* in_sizes, int n_in,
                              void* d_out, int out_size, void* d_ws, size_t ws_size,
                              hipStream_t stream) {
    (void)in_sizes; (void)n_in; (void)out_size;
    const float* vision   = (const float*)d_in[0];
    const float* w_vision = (const float*)d_in[1];
    const float* b_vision = (const float*)d_in[2];
    const float* text     = (const float*)d_in[3];
    const float* w_text   = (const float*)d_in[4];
    const float* b_text   = (const float*)d_in[5];
    const float* audio    = (const float*)d_in[6];
    const float* w_audio  = (const float*)d_in[7];
    const float* b_audio  = (const float*)d_in[8];
    const float* wq = (const float*)d_in[9];
    const float* bq = (const float*)d_in[10];
    const float* wk = (const float*)d_in[11];
    const float* bk = (const float*)d_in[12];
    const float* wv = (const float*)d_in[13];
    const float* bv = (const float*)d_in[14];
    const float* wo = (const float*)d_in[15];
    const float* bo = (const float*)d_in[16];
    const float* temp  = (const float*)d_in[17];
    const float* attnw = (const float*)d_in[18];

    const size_t SD = (size_t)2048 * 1024;     // 1<<21
    const size_t FE = 24 * SD;                 // B*M*S*D
    const size_t QE = 8 * SD;                  // B*S*D
    const size_t WT = 6553600;                 // transposed bf16 weights

    const size_t need = (2*FE + QE + WT) * 2 + ((size_t)16384*16*3 + 512*9 + 32) * 4;
    if (ws_size < need) return;

    (void)hipFuncSetAttribute((const void*)gemm_bd<0>,
                              hipFuncAttributeMaxDynamicSharedMemorySize, 65536);
    (void)hipFuncSetAttribute((const void*)gemm_bd<1>,
                              hipFuncAttributeMaxDynamicSharedMemorySize, 65536);

    unsigned short* feats = (unsigned short*)d_ws;
    unsigned short* KV    = feats + FE;      // inb -> K -> V
    unsigned short* Qb    = KV + FE;         // Q, then fused in place
    unsigned short* wT    = Qb + QE;
    float* attn  = (float*)(wT + WT);
    float* gpart = attn + (size_t)16384*16*3;
    float* coef  = gpart + 512*9;
    float* outp  = (float*)d_out;

    unsigned short* wT_v = wT;                 // 1024x768
    unsigned short* wT_t = wT_v + 786432;      // 1024x512
    unsigned short* wT_a = wT_t + 524288;      // 1024x1024
    unsigned short* wT_q = wT_a + 1048576;
    unsigned short* wT_k = wT_q + 1048576;
    unsigned short* wT_vv= wT_k + 1048576;
    unsigned short* wT_o = wT_vv+ 1048576;

    unsigned short* in_v = KV;                 // 16384x768
    unsigned short* in_t = in_v + (size_t)16384*768;
    unsigned short* in_a = in_t + (size_t)16384*512;

    dim3 blk(256);

    WtArgs wa;
    wa.src[0]=w_vision; wa.src[1]=w_text; wa.src[2]=w_audio; wa.src[3]=wq;
    wa.src[4]=wk; wa.src[5]=wv; wa.src[6]=wo;
    wa.dst[0]=wT_v; wa.dst[1]=wT_t; wa.dst[2]=wT_a; wa.dst[3]=wT_q;
    wa.dst[4]=wT_k; wa.dst[5]=wT_vv; wa.dst[6]=wT_o;
    wa.K[0]=768; wa.K[1]=512; wa.K[2]=1024; wa.K[3]=1024; wa.K[4]=1024;
    wa.K[5]=1024; wa.K[6]=1024;
    wa.cum[0]=0; wa.cum[1]=768; wa.cum[2]=1280; wa.cum[3]=2304; wa.cum[4]=3328;
    wa.cum[5]=4352; wa.cum[6]=5376; wa.cum[7]=6400;
    wtrans_all<<<6400, blk, 0, stream>>>(wa);

    CvtArgs ca;
    ca.s0 = vision; ca.s1 = text; ca.s2 = audio;
    ca.c0 = (long)16384*768/8;
    ca.c1 = ca.c0 + (long)16384*512/8;
    ca.ntot = ca.c1 + (long)16384*1024/8;
    cvt_all<<<4096, blk, 0, stream>>>(ca, in_v);

    gemm_bd<0><<<256, 512, 65536, stream>>>(in_v, wT_v, b_vision, feats + 0*SD,
                                            1024, 768, 16384, 0, 2048, 6144, 12);
    gemm_bd<0><<<256, 512, 65536, stream>>>(in_t, wT_t, b_text,   feats + 1*SD,
                                            1024, 512, 16384, 0, 2048, 6144, 8);
    gemm_bd<0><<<256, 512, 65536, stream>>>(in_a, wT_a, b_audio,  feats + 2*SD,
                                            1024, 1024, 16384, 0, 2048, 6144, 16);
    gemm_bd<0><<<256, 512, 65536, stream>>>(feats, wT_q, bq, Qb,
                                            1024, 1024, 2048, 6144, 16384, 0, 16);
    gemm_bd<0><<<768, 512, 65536, stream>>>(feats, wT_k, bk, KV,
                                            1024, 1024, 49152, 0, 49152, 0, 16);
    scores_gram_kernel<<<4608, blk, 0, stream>>>(Qb, KV, temp, attn, feats, gpart);
    weights_kernel<<<1, 64, 0, stream>>>(gpart, temp, attnw, coef);
    gemm_bd<0><<<768, 512, 65536, stream>>>(feats, wT_vv, bv, KV,
                                            1024, 1024, 49152, 0, 49152, 0, 16);
    fusemha_kernel<<<4096, blk, 0, stream>>>(KV, feats, attn, coef, Qb);
    gemm_bd<1><<<256, 512, 65536, stream>>>(Qb, wT_o, bo, outp,
                                            1024, 1024, 16384, 0, 16384, 0, 16);
}

// Round 17
// 506.557 us; speedup vs baseline: 1.1574x; 1.1574x over previous
//
#include <hip/hip_runtime.h>

// GeometricModalityFusion on MI355X — round 17: combined-weight factorization
// (K/V/Q contract over d_m via precomputed W_m·w{k,v,q}; −13% GEMM work),
// r7 GEMM schedule unchanged. Fallback to r13 path if ws too small.
// f32 in/out; bf16 16x16x32 MFMA. B=8, S=2048, D=1024, H=16, M=3.

typedef __attribute__((ext_vector_type(8))) short bf16x8;
typedef __attribute__((ext_vector_type(4))) float f32x4;
typedef __attribute__((ext_vector_type(8))) unsigned short u16x8;

__device__ __forceinline__ float b2f(unsigned short u) {
    return __uint_as_float(((unsigned int)u) << 16);
}
__device__ __forceinline__ unsigned short f2b(float f) {
    unsigned int x = __float_as_uint(f);
    x += 0x7fffu + ((x >> 16) & 1u);   // RNE
    return (unsigned short)(x >> 16);
}
__device__ __forceinline__ void gl_lds16(const unsigned short* g, const unsigned short* l) {
    __builtin_amdgcn_global_load_lds(
        (const __attribute__((address_space(1))) unsigned int*)g,
        (__attribute__((address_space(3))) unsigned int*)(unsigned short*)l, 16, 0, 0);
}

// ---------------------------------------------------------------------------
// merged weight transpose+convert: 7 matrices f32 [K][1024] -> bf16 [1024][K]
// ---------------------------------------------------------------------------
struct WtArgs {
    const float* src[7];
    unsigned short* dst[7];
    int K[7];
    int cum[8];
};

__global__ __launch_bounds__(256) void wtrans_all(WtArgs a)
{
    __shared__ float t[32][33];
    const int bid = blockIdx.x;
    int m = 0;
    while (bid >= a.cum[m + 1]) ++m;
    const int local = bid - a.cum[m];
    const int K = a.K[m];
    const int kb = K >> 5;
    const int k0 = (local % kb) * 32;
    const int n0 = (local / kb) * 32;
    const float* in = a.src[m];
    unsigned short* out = a.dst[m];
    const int N = 1024;

    const int tx = threadIdx.x & 31, ty = threadIdx.x >> 5;
#pragma unroll
    for (int r = ty; r < 32; r += 8)
        t[r][tx] = in[(size_t)(k0 + r) * N + n0 + tx];
    __syncthreads();
#pragma unroll
    for (int r = ty; r < 32; r += 8)
        out[(size_t)(n0 + r) * K + k0 + tx] = f2b(t[tx][r]);
}

// merged f32 -> bf16 convert over 3 source segments into one contiguous dst
struct CvtArgs {
    const float* s0; const float* s1; const float* s2;
    long c0, c1, ntot;
};

__global__ __launch_bounds__(256) void cvt_all(CvtArgs a, unsigned short* __restrict__ dst)
{
    for (long i = (long)blockIdx.x * 256 + threadIdx.x; i < a.ntot; i += (long)gridDim.x * 256) {
        const float* src; long off;
        if (i < a.c0)      { src = a.s0; off = i; }
        else if (i < a.c1) { src = a.s1; off = i - a.c0; }
        else               { src = a.s2; off = i - a.c1; }
        const float4 v0 = *reinterpret_cast<const float4*>(src + off * 8);
        const float4 v1 = *reinterpret_cast<const float4*>(src + off * 8 + 4);
        u16x8 w;
        w[0]=f2b(v0.x); w[1]=f2b(v0.y); w[2]=f2b(v0.z); w[3]=f2b(v0.w);
        w[4]=f2b(v1.x); w[5]=f2b(v1.y); w[6]=f2b(v1.z); w[7]=f2b(v1.w);
        *reinterpret_cast<u16x8*>(dst + i * 8) = w;
    }
}

// ---------------------------------------------------------------------------
// 256x256 pipelined GEMM (r7 schedule): C[r][n]=sum_k A[amap(r)][k]*Bt[n][k]+bias[n]
// Bt rows may live in a wider matrix: bt_stride >= Kdim (element row pitch).
// bias may be nullptr (treated as 0). XCD swizzle only when gridDim.x%8==0.
// ---------------------------------------------------------------------------
template<int CF32>
__global__ __launch_bounds__(512, 2) void gemm8p(
    const unsigned short* __restrict__ A, const unsigned short* __restrict__ Bt,
    const float* __restrict__ bias, void* __restrict__ Cout,
    int Ndim, int Kdim, int bt_stride, int a_rpb, int a_bs, int c_rpb, int c_bs, int nt)
{
    extern __shared__ __align__(16) unsigned short lds[];   // A: [0,32768) B: [32768,65536) elems

    const int tid  = threadIdx.x;
    const int lane = tid & 63;
    const int w    = tid >> 6;
    const int wm = w >> 2, wn = w & 3;
    const int lr = lane & 15, lk = lane >> 4;

    const int ncol = Ndim >> 8;
    int wgid;
    if ((gridDim.x & 7) == 0) {
        const int cpx = gridDim.x >> 3;
        wgid = (blockIdx.x & 7) * cpx + (blockIdx.x >> 3);
    } else {
        wgid = blockIdx.x;
    }
    const int m0 = (wgid / ncol) << 8;
    const int n0 = (wgid % ncol) << 8;

    const int srow  = tid >> 3;
    const int gslot = (tid & 7) ^ (srow & 7);
    const int gr0   = m0 + srow;
    const size_t asrc0 = ((size_t)((gr0 / a_rpb) * a_bs + (gr0 % a_rpb))) * Kdim + gslot * 8;
    const size_t bsrc0 = ((size_t)(n0 + srow)) * bt_stride + gslot * 8;
    const size_t arstep = (size_t)64 * Kdim;
    const size_t brstep = (size_t)64 * bt_stride;
    const int sdst = (w << 9);   // wave-uniform LDS base (HW adds lane*16B)

#define STAGE_A(doff, j, tt) gl_lds16(A  + asrc0 + (size_t)(j)*arstep + (size_t)(tt)*64, \
                                      lds + (doff) + (j)*4096 + sdst)
#define STAGE_B(doff, j, tt) gl_lds16(Bt + bsrc0 + (size_t)(j)*brstep + (size_t)(tt)*64, \
                                      lds + 32768 + (doff) + (j)*4096 + sdst)

    const int sel0 = ((lk)     ^ (lr & 7)) * 8;
    const int sel1 = ((lk + 4) ^ (lr & 7)) * 8;
    const int arow = (wm * 128 + lr) * 64;
    const int brow = (wn * 64  + lr) * 64;

#define LDV(off) (*reinterpret_cast<const bf16x8*>(lds + (off)))

    f32x4 acc[8][4];
    const f32x4 zero = {0.f, 0.f, 0.f, 0.f};
#pragma unroll
    for (int a = 0; a < 8; ++a)
#pragma unroll
        for (int b = 0; b < 4; ++b) acc[a][b] = zero;

    bf16x8 af[4][2], bfA[2][2], bfB[2][2];

#define READ_AF(base, roff) \
    _Pragma("unroll") \
    for (int a = 0; a < 4; ++a) { \
        af[a][0] = LDV((base) + arow + ((roff) + a) * 1024 + sel0); \
        af[a][1] = LDV((base) + arow + ((roff) + a) * 1024 + sel1); \
    }
#define READ_BFA(base) \
    _Pragma("unroll") \
    for (int b = 0; b < 2; ++b) { \
        bfA[b][0] = LDV(32768 + (base) + brow + b * 1024 + sel0); \
        bfA[b][1] = LDV(32768 + (base) + brow + b * 1024 + sel1); \
    }
#define READ_BFB(base) \
    _Pragma("unroll") \
    for (int b = 0; b < 2; ++b) { \
        bfB[b][0] = LDV(32768 + (base) + brow + (2 + b) * 1024 + sel0); \
        bfB[b][1] = LDV(32768 + (base) + brow + (2 + b) * 1024 + sel1); \
    }

#define MFMA_Q(RA, CB, BF) \
    _Pragma("unroll") \
    for (int a = 0; a < 4; ++a) { \
        _Pragma("unroll") \
        for (int b = 0; b < 2; ++b) { \
            acc[RA+a][CB+b] = __builtin_amdgcn_mfma_f32_16x16x32_bf16(af[a][0], BF[b][0], acc[RA+a][CB+b], 0, 0, 0); \
            acc[RA+a][CB+b] = __builtin_amdgcn_mfma_f32_16x16x32_bf16(af[a][1], BF[b][1], acc[RA+a][CB+b], 0, 0, 0); \
        } \
    }

    // prologue: stage tile 0 into buf 0; drain; barrier; pre-read R0
#pragma unroll
    for (int j = 0; j < 4; ++j) STAGE_A(0, j, 0);
#pragma unroll
    for (int j = 0; j < 4; ++j) STAGE_B(0, j, 0);
    asm volatile("s_waitcnt vmcnt(0)" ::: "memory");
    __builtin_amdgcn_s_barrier();
    READ_AF(0, 0);
    READ_BFA(0);

    for (int t = 0; t < nt; ++t) {
        const int cur = (t & 1) << 14;
        const int nb  = ((t + 1) & 1) << 14;
        const bool pf = (t + 1) < nt;

        // ph0: MFMA Q0 ; read bfB ; stage A(t+1)
        __builtin_amdgcn_s_setprio(1);
        MFMA_Q(0, 0, bfA);
        __builtin_amdgcn_s_setprio(0);
        READ_BFB(cur);
        if (pf) {
            STAGE_A(nb, 0, t+1); STAGE_A(nb, 1, t+1);
            STAGE_A(nb, 2, t+1); STAGE_A(nb, 3, t+1);
        }

        // ph1: MFMA Q1 ; read af47 ; stage B(t+1)
        __builtin_amdgcn_s_setprio(1);
        MFMA_Q(0, 2, bfB);
        __builtin_amdgcn_s_setprio(0);
        READ_AF(cur, 4);
        if (pf) {
            STAGE_B(nb, 0, t+1); STAGE_B(nb, 1, t+1);
            STAGE_B(nb, 2, t+1); STAGE_B(nb, 3, t+1);
        }

        // ph2+3: MFMA Q2, Q3
        __builtin_amdgcn_s_setprio(1);
        MFMA_Q(4, 2, bfB);
        MFMA_Q(4, 0, bfA);
        __builtin_amdgcn_s_setprio(0);

        // boundary
        asm volatile("s_waitcnt vmcnt(0)" ::: "memory");
        __builtin_amdgcn_s_barrier();
        if (pf) {
            READ_AF(nb, 0);
            READ_BFA(nb);
        }
    }

    // epilogue: C/D layout col=lane&15, row=(lane>>4)*4+r; bias hoisted
    const int grow0 = m0 + wm * 128;
    const int crow0 = (grow0 / c_rpb) * c_bs + (grow0 % c_rpb);
    float bv[4];
#pragma unroll
    for (int b = 0; b < 4; ++b)
        bv[b] = bias ? bias[n0 + wn * 64 + b * 16 + lr] : 0.f;
#pragma unroll
    for (int a = 0; a < 8; ++a) {
#pragma unroll
        for (int b = 0; b < 4; ++b) {
            const int gcol = n0 + wn * 64 + b * 16 + lr;
#pragma unroll
            for (int r = 0; r < 4; ++r) {
                const int crow = crow0 + a * 16 + lk * 4 + r;
                if constexpr (CF32) {
                    ((float*)Cout)[(size_t)crow * Ndim + gcol] = acc[a][b][r] + bv[b];
                } else {
                    ((unsigned short*)Cout)[(size_t)crow * Ndim + gcol] = f2b(acc[a][b][r] + bv[b]);
                }
            }
        }
    }
#undef STAGE_A
#undef STAGE_B
#undef LDV
#undef READ_AF
#undef READ_BFA
#undef READ_BFB
#undef MFMA_Q
}

// ---------------------------------------------------------------------------
// Combined scores (blocks 0..4095) + gram partials (blocks 4096..4607).
// ---------------------------------------------------------------------------
__global__ __launch_bounds__(256) void scores_gram_kernel(
    const unsigned short* __restrict__ Q, const unsigned short* __restrict__ Kb,
    const float* __restrict__ temp, float* __restrict__ attn,
    const unsigned short* __restrict__ feats, float* __restrict__ gpart)
{
    __shared__ float red[4][9];
    if (blockIdx.x < 4096) {
        const int lane = threadIdx.x & 63;
        const int w  = blockIdx.x * 4 + (threadIdx.x >> 6);
        const int b  = w >> 11;
        const int s  = w & 2047;
        const float t = fabsf(temp[0]);
        const float inv = 1.f / (8.f * t);
        const size_t qbase = (((size_t)w) << 10) + lane * 8;
        const u16x8 qv0 = *reinterpret_cast<const u16x8*>(Q + qbase);
        const u16x8 qv1 = *reinterpret_cast<const u16x8*>(Q + qbase + 512);
        float sc0[3], sc1[3];
#pragma unroll
        for (int m = 0; m < 3; ++m) {
            const size_t koff = ((((size_t)(b*3 + m) << 11) + s) << 10) + lane * 8;
            const u16x8 kv0 = *reinterpret_cast<const u16x8*>(Kb + koff);
            const u16x8 kv1 = *reinterpret_cast<const u16x8*>(Kb + koff + 512);
            float p0 = 0.f, p1 = 0.f;
#pragma unroll
            for (int j = 0; j < 8; ++j) {
                p0 = fmaf(b2f(qv0[j]), b2f(kv0[j]), p0);
                p1 = fmaf(b2f(qv1[j]), b2f(kv1[j]), p1);
            }
            p0 += __shfl_xor(p0, 1); p0 += __shfl_xor(p0, 2); p0 += __shfl_xor(p0, 4);
            p1 += __shfl_xor(p1, 1); p1 += __shfl_xor(p1, 2); p1 += __shfl_xor(p1, 4);
            sc0[m] = p0 * inv;
            sc1[m] = p1 * inv;
        }
        const float mx0 = fmaxf(sc0[0], fmaxf(sc0[1], sc0[2]));
        const float a0 = expf(sc0[0]-mx0), a1 = expf(sc0[1]-mx0), a2 = expf(sc0[2]-mx0);
        const float is0 = 1.f / (a0 + a1 + a2);
        const float mx1 = fmaxf(sc1[0], fmaxf(sc1[1], sc1[2]));
        const float c0 = expf(sc1[0]-mx1), c1 = expf(sc1[1]-mx1), c2 = expf(sc1[2]-mx1);
        const float is1 = 1.f / (c0 + c1 + c2);
        if ((lane & 7) == 0) {
            const int h0 = lane >> 3;
            const size_t b0 = ((size_t)w * 16 + h0) * 3;
            const size_t b1 = ((size_t)w * 16 + 8 + h0) * 3;
            attn[b0+0] = a0 * is0; attn[b0+1] = a1 * is0; attn[b0+2] = a2 * is0;
            attn[b1+0] = c0 * is1; attn[b1+1] = c1 * is1; attn[b1+2] = c2 * is1;
        }
        return;
    }

    const int gb    = blockIdx.x - 4096;
    const int b     = gb >> 6;
    const int chunk = gb & 63;
    const int wave  = threadIdx.x >> 6;
    const int lane  = threadIdx.x & 63;
    float acc[9];
#pragma unroll
    for (int i = 0; i < 9; ++i) acc[i] = 0.f;
    const int s_base = chunk * 32 + wave * 8;
    const size_t bbase = ((size_t)(b*3)) << 21;
    for (int ti = 0; ti < 8; ++ti) {
        const size_t rowoff = ((size_t)(s_base + ti)) << 10;
        float g[6] = {0.f,0.f,0.f,0.f,0.f,0.f};
#pragma unroll
        for (int half = 0; half < 2; ++half) {
            const int d = (half << 9) + (lane << 3);
            u16x8 v0 = *(const u16x8*)(feats + bbase + rowoff + d);
            u16x8 v1 = *(const u16x8*)(feats + bbase + ((size_t)1<<21) + rowoff + d);
            u16x8 v2 = *(const u16x8*)(feats + bbase + ((size_t)2<<21) + rowoff + d);
#pragma unroll
            for (int j = 0; j < 8; ++j) {
                float x0 = b2f(v0[j]), x1 = b2f(v1[j]), x2 = b2f(v2[j]);
                g[0] = fmaf(x0,x0,g[0]); g[1] = fmaf(x0,x1,g[1]); g[2] = fmaf(x0,x2,g[2]);
                g[3] = fmaf(x1,x1,g[3]); g[4] = fmaf(x1,x2,g[4]); g[5] = fmaf(x2,x2,g[5]);
            }
        }
#pragma unroll
        for (int i = 0; i < 6; ++i) {
#pragma unroll
            for (int o = 32; o > 0; o >>= 1) g[i] += __shfl_xor(g[i], o);
        }
        const float n0 = fmaxf(sqrtf(g[0]), 1e-12f);
        const float n1 = fmaxf(sqrtf(g[3]), 1e-12f);
        const float n2 = fmaxf(sqrtf(g[5]), 1e-12f);
        acc[0]+=g[0]; acc[1]+=g[1]; acc[2]+=g[2]; acc[3]+=g[3]; acc[4]+=g[4]; acc[5]+=g[5];
        acc[6]+=g[1]/(n0*n1); acc[7]+=g[2]/(n0*n2); acc[8]+=g[4]/(n1*n2);
    }
    if (lane == 0) {
#pragma unroll
        for (int i = 0; i < 9; ++i) red[wave][i] = acc[i];
    }
    __syncthreads();
    if (threadIdx.x == 0) {
#pragma unroll
        for (int i = 0; i < 9; ++i)
            gpart[gb * 9 + i] = red[0][i] + red[1][i] + red[2][i] + red[3][i];
    }
}

// per-batch scalar weights: angular (aw) + cayley (cw) + fusion softmax (fw)
__global__ void weights_kernel(const float* __restrict__ gpart,
                               const float* __restrict__ temp,
                               const float* __restrict__ attnw,
                               float* __restrict__ coef)
{
    const int b = threadIdx.x;
    if (b >= 8) return;
    const float t = fabsf(temp[0]);

    float a0 = attnw[0], a1 = attnw[1], a2 = attnw[2];
    float amx = fmaxf(a0, fmaxf(a1, a2));
    float fe0 = expf(a0-amx), fe1 = expf(a1-amx), fe2 = expf(a2-amx);
    float fs = fe0 + fe1 + fe2;
    float fw0 = fe0/fs, fw1 = fe1/fs, fw2 = fe2/fs;

    float g[9];
#pragma unroll
    for (int i = 0; i < 9; ++i) {
        float ssum = 0.f;
        for (int c = 0; c < 64; ++c) ssum += gpart[(b*64 + c)*9 + i];
        g[i] = ssum;
    }
    const float G[3][3] = {{g[0],g[1],g[2]},{g[1],g[3],g[4]},{g[2],g[4],g[5]}};

    const float c01 = g[6] / 2048.f, c02 = g[7] / 2048.f, c12 = g[8] / 2048.f;
    const float lo = -1.f + 1e-7f, hi = 1.f - 1e-7f;
    const float ang01 = acosf(fminf(fmaxf(c01, lo), hi));
    const float ang02 = acosf(fminf(fmaxf(c02, lo), hi));
    const float ang12 = acosf(fminf(fmaxf(c12, lo), hi));
    const float e01 = expf(-ang01/t), e02 = expf(-ang02/t), e12 = expf(-ang12/t);
    const float l0 = e01*(-0.75f) + e02*(0.75f);
    const float l1 = e01*(1.0f)   + e12*(0.75f);
    const float l2 = e02*(1.0f)   + e12*(-0.75f);
    const float lm = fmaxf(l0, fmaxf(l1, l2));
    const float ae0 = expf(l0-lm), ae1 = expf(l1-lm), ae2 = expf(l2-lm);
    const float as = ae0 + ae1 + ae2;
    const float aw[3] = {ae0/as, ae1/as, ae2/as};

    float vol[3];
#pragma unroll
    for (int i = 0; i < 3; ++i) {
        float Ac[3][3] = {{0.f,0.f,0.f},{0.f,0.f,0.f},{0.f,0.f,0.f}};
        Ac[0][i] = 1.f;
        Ac[1][i] = 0.70710678f; Ac[1][(i+1)%3] += 0.70710678f;
        Ac[2][(i+2)%3] = 1.f;
        float Gi[3][3];
        for (int p = 0; p < 3; ++p)
            for (int q = 0; q < 3; ++q) {
                float ssum = 0.f;
                for (int k = 0; k < 3; ++k)
                    for (int l = 0; l < 3; ++l)
                        ssum += Ac[p][k] * G[k][l] * Ac[q][l];
                Gi[p][q] = ssum;
            }
        float ds = 0.f;
        for (int p = 0; p < 3; ++p)
            for (int q = 0; q < 3; ++q)
                ds += Gi[p][p] + Gi[q][q] - 2.f*Gi[p][q];
        vol[i] = ds / 9.f;
    }
    const float lv0 = vol[0]/t, lv1 = vol[1]/t, lv2 = vol[2]/t;
    const float vm = fmaxf(lv0, fmaxf(lv1, lv2));
    const float ce0 = expf(lv0-vm), ce1 = expf(lv1-vm), ce2 = expf(lv2-vm);
    const float cs = ce0 + ce1 + ce2;
    const float cw[3] = {ce0/cs, ce1/cs, ce2/cs};

    coef[b*4+0] = fw1*aw[0] + fw2*cw[0];
    coef[b*4+1] = fw1*aw[1] + fw2*cw[1];
    coef[b*4+2] = fw1*aw[2] + fw2*cw[2];
    coef[b*4+3] = fw0;
}

// ---------------------------------------------------------------------------
// Merged mha+fuse.
// ---------------------------------------------------------------------------
__global__ __launch_bounds__(256) void fusemha_kernel(
    const unsigned short* __restrict__ Vb, const unsigned short* __restrict__ feats,
    const float* __restrict__ attn, const float* __restrict__ coef,
    unsigned short* __restrict__ fused)
{
    const int lane = threadIdx.x & 63;
    const int w  = blockIdx.x * 4 + (threadIdx.x >> 6);
    const int b  = w >> 11;
    const int s  = w & 2047;
    const int h0 = lane >> 3;
    const float fw0 = coef[b*4+3];
    const float c0 = coef[b*4+0], c1 = coef[b*4+1], c2 = coef[b*4+2];
    const size_t ab0 = ((size_t)w * 16 + h0) * 3;
    const size_t ab1 = ((size_t)w * 16 + 8 + h0) * 3;
    const float a00 = fw0*attn[ab0+0], a01 = fw0*attn[ab0+1], a02 = fw0*attn[ab0+2];
    const float a10 = fw0*attn[ab1+0], a11 = fw0*attn[ab1+1], a12 = fw0*attn[ab1+2];
    const size_t base = ((((size_t)(b*3) << 11) + s) << 10) + lane * 8;
    const size_t ms = (size_t)1 << 21;
    const u16x8 v00 = *reinterpret_cast<const u16x8*>(Vb + base);
    const u16x8 v01 = *reinterpret_cast<const u16x8*>(Vb + base + ms);
    const u16x8 v02 = *reinterpret_cast<const u16x8*>(Vb + base + 2*ms);
    const u16x8 v10 = *reinterpret_cast<const u16x8*>(Vb + base + 512);
    const u16x8 v11 = *reinterpret_cast<const u16x8*>(Vb + base + ms + 512);
    const u16x8 v12 = *reinterpret_cast<const u16x8*>(Vb + base + 2*ms + 512);
    const u16x8 f00 = *reinterpret_cast<const u16x8*>(feats + base);
    const u16x8 f01 = *reinterpret_cast<const u16x8*>(feats + base + ms);
    const u16x8 f02 = *reinterpret_cast<const u16x8*>(feats + base + 2*ms);
    const u16x8 f10 = *reinterpret_cast<const u16x8*>(feats + base + 512);
    const u16x8 f11 = *reinterpret_cast<const u16x8*>(feats + base + ms + 512);
    const u16x8 f12 = *reinterpret_cast<const u16x8*>(feats + base + 2*ms + 512);
    u16x8 o0, o1;
#pragma unroll
    for (int j = 0; j < 8; ++j) {
        o0[j] = f2b(a00*b2f(v00[j]) + a01*b2f(v01[j]) + a02*b2f(v02[j])
                  + c0*b2f(f00[j]) + c1*b2f(f01[j]) + c2*b2f(f02[j]));
        o1[j] = f2b(a10*b2f(v10[j]) + a11*b2f(v11[j]) + a12*b2f(v12[j])
                  + c0*b2f(f10[j]) + c1*b2f(f11[j]) + c2*b2f(f12[j]));
    }
    const size_t qoff = (((size_t)w) << 10) + lane * 8;
    *reinterpret_cast<u16x8*>(fused + qoff) = o0;
    *reinterpret_cast<u16x8*>(fused + qoff + 512) = o1;
}

// ---------------------------------------------------------------------------
extern "C" void kernel_launch(void* const* d_in, const int* in_sizes, int n_in,
                              void* d_out, int out_size, void* d_ws, size_t ws_size,
                              hipStream_t stream) {
    (void)in_sizes; (void)n_in; (void)out_size;
    const float* vision   = (const float*)d_in[0];
    const float* w_vision = (const float*)d_in[1];
    const float* b_vision = (const float*)d_in[2];
    const float* text     = (const float*)d_in[3];
    const float* w_text   = (const float*)d_in[4];
    const float* b_text   = (const float*)d_in[5];
    const float* audio    = (const float*)d_in[6];
    const float* w_audio  = (const float*)d_in[7];
    const float* b_audio  = (const float*)d_in[8];
    const float* wq = (const float*)d_in[9];
    const float* bq = (const float*)d_in[10];
    const float* wk = (const float*)d_in[11];
    const float* bk = (const float*)d_in[12];
    const float* wv = (const float*)d_in[13];
    const float* bv = (const float*)d_in[14];
    const float* wo = (const float*)d_in[15];
    const float* bo = (const float*)d_in[16];
    const float* temp  = (const float*)d_in[17];
    const float* attnw = (const float*)d_in[18];

    const size_t SD = (size_t)2048 * 1024;     // 1<<21
    const size_t FE = 24 * SD;                 // B*M*S*D
    const size_t QE = 8 * SD;                  // B*S*D
    const size_t WT = 6553600;                 // transposed bf16 weights
    const size_t INC = (size_t)16384 * 2304;   // concatenated bf16 inputs
    const size_t WRAW = (size_t)2304 * 1024;   // stacked raw bf16 weights
    const size_t WCAT = (size_t)3072 * 2304;   // combined weights

    const size_t small_f32 = ((size_t)16384*16*3 + 512*9 + 32) * 4;
    const size_t need_new = (FE + FE + QE + INC + WT + WRAW + WCAT) * 2 + small_f32;
    const size_t need_old = (2*FE + QE + WT) * 2 + small_f32;
    if (ws_size < need_old) return;
    const bool big = (ws_size >= need_new);

    (void)hipFuncSetAttribute((const void*)gemm8p<0>,
                              hipFuncAttributeMaxDynamicSharedMemorySize, 131072);
    (void)hipFuncSetAttribute((const void*)gemm8p<1>,
                              hipFuncAttributeMaxDynamicSharedMemorySize, 131072);

    dim3 blk(256);
    float* outp = (float*)d_out;

    if (big) {
        unsigned short* feats = (unsigned short*)d_ws;
        unsigned short* KV    = feats + FE;
        unsigned short* Qb    = KV + FE;
        unsigned short* inc   = Qb + QE;          // [in_v | in_t | in_a]
        unsigned short* wT    = inc + INC;        // [v t a o k vv q]
        unsigned short* wraw  = wT + WT;          // [Wv ; Wt ; Wa] bf16 raw
        unsigned short* wcat  = wraw + WRAW;      // [k;v;q]x[vis|txt|aud] combined
        float* attn  = (float*)(wcat + WCAT);
        float* gpart = attn + (size_t)16384*16*3;
        float* coef  = gpart + 512*9;

        unsigned short* wT_v = wT;
        unsigned short* wT_t = wT_v + 786432;
        unsigned short* wT_a = wT_t + 524288;
        unsigned short* wT_o = wT_a + 1048576;
        unsigned short* wT_k = wT_o + 1048576;    // k,vv,q contiguous = A_cat
        unsigned short* in_v = inc;
        unsigned short* in_t = in_v + (size_t)16384*768;
        unsigned short* in_a = in_t + (size_t)16384*512;

        // 1) weight transpose+convert (order: v t a o k vv q)
        WtArgs wa;
        wa.src[0]=w_vision; wa.src[1]=w_text; wa.src[2]=w_audio; wa.src[3]=wo;
        wa.src[4]=wk; wa.src[5]=wv; wa.src[6]=wq;
        wa.dst[0]=wT_v; wa.dst[1]=wT_t; wa.dst[2]=wT_a; wa.dst[3]=wT_o;
        wa.dst[4]=wT_k; wa.dst[5]=wT_k+1048576; wa.dst[6]=wT_k+2097152;
        wa.K[0]=768; wa.K[1]=512; wa.K[2]=1024; wa.K[3]=1024; wa.K[4]=1024;
        wa.K[5]=1024; wa.K[6]=1024;
        wa.cum[0]=0; wa.cum[1]=768; wa.cum[2]=1280; wa.cum[3]=2304; wa.cum[4]=3328;
        wa.cum[5]=4352; wa.cum[6]=5376; wa.cum[7]=6400;
        wtrans_all<<<6400, blk, 0, stream>>>(wa);

        // 2) inputs f32->bf16 ; 3) raw weights f32->bf16 (stacked [2304][1024])
        CvtArgs ci;
        ci.s0 = vision; ci.s1 = text; ci.s2 = audio;
        ci.c0 = (long)16384*768/8;
        ci.c1 = ci.c0 + (long)16384*512/8;
        ci.ntot = ci.c1 + (long)16384*1024/8;
        cvt_all<<<4096, blk, 0, stream>>>(ci, in_v);
        CvtArgs cw2;
        cw2.s0 = w_vision; cw2.s1 = w_text; cw2.s2 = w_audio;
        cw2.c0 = (long)768*1024/8;
        cw2.c1 = cw2.c0 + (long)512*1024/8;
        cw2.ntot = cw2.c1 + (long)1024*1024/8;
        cvt_all<<<1152, blk, 0, stream>>>(cw2, wraw);

        // 4) combined weights: wcat[3072][2304] = [wkT;wvT;wqT] x wraw^T
        gemm8p<0><<<108, 512, 131072, stream>>>(wT_k, wraw, nullptr, wcat,
                                                2304, 1024, 1024, 3072, 0, 3072, 0, 16);
        // 5) projections -> feats (row scatter 2048/6144)
        gemm8p<0><<<256, 512, 131072, stream>>>(in_v, wT_v, b_vision, feats + 0*SD,
                                                1024, 768, 768, 16384, 0, 2048, 6144, 12);
        gemm8p<0><<<256, 512, 131072, stream>>>(in_t, wT_t, b_text,   feats + 1*SD,
                                                1024, 512, 512, 16384, 0, 2048, 6144, 8);
        gemm8p<0><<<256, 512, 131072, stream>>>(in_a, wT_a, b_audio,  feats + 2*SD,
                                                1024, 1024, 1024, 16384, 0, 2048, 6144, 16);
        // 6) Q = in_v @ (Wv.wq) : q-section rows (2048..3071), vision cols
        gemm8p<0><<<256, 512, 131072, stream>>>(in_v, wcat + (size_t)2048*2304, bq, Qb,
                                                1024, 768, 2304, 16384, 0, 16384, 0, 12);
        // 7) K_m = in_m @ (Wm.wk) : k-section rows (0..1023)
        gemm8p<0><<<256, 512, 131072, stream>>>(in_v, wcat + 0,    bk, KV + 0*SD,
                                                1024, 768, 2304, 16384, 0, 2048, 6144, 12);
        gemm8p<0><<<256, 512, 131072, stream>>>(in_t, wcat + 768,  bk, KV + 1*SD,
                                                1024, 512, 2304, 16384, 0, 2048, 6144, 8);
        gemm8p<0><<<256, 512, 131072, stream>>>(in_a, wcat + 1280, bk, KV + 2*SD,
                                                1024, 1024, 2304, 16384, 0, 2048, 6144, 16);
        // 8) scores+gram ; 9) per-batch weights
        scores_gram_kernel<<<4608, blk, 0, stream>>>(Qb, KV, temp, attn, feats, gpart);
        weights_kernel<<<1, 64, 0, stream>>>(gpart, temp, attnw, coef);
        // 10) V_m = in_m @ (Wm.wv) : v-section rows (1024..2047)
        gemm8p<0><<<256, 512, 131072, stream>>>(in_v, wcat + (size_t)1024*2304,        bv, KV + 0*SD,
                                                1024, 768, 2304, 16384, 0, 2048, 6144, 12);
        gemm8p<0><<<256, 512, 131072, stream>>>(in_t, wcat + (size_t)1024*2304 + 768,  bv, KV + 1*SD,
                                                1024, 512, 2304, 16384, 0, 2048, 6144, 8);
        gemm8p<0><<<256, 512, 131072, stream>>>(in_a, wcat + (size_t)1024*2304 + 1280, bv, KV + 2*SD,
                                                1024, 1024, 2304, 16384, 0, 2048, 6144, 16);
        // 11) merged mha+fusion -> Qb ; 12) output projection
        fusemha_kernel<<<4096, blk, 0, stream>>>(KV, feats, attn, coef, Qb);
        gemm8p<1><<<256, 512, 131072, stream>>>(Qb, wT_o, bo, outp,
                                                1024, 1024, 1024, 16384, 0, 16384, 0, 16);
        return;
    }

    // ---------------- fallback: r13 layout/sequence ----------------
    unsigned short* feats = (unsigned short*)d_ws;
    unsigned short* KV    = feats + FE;
    unsigned short* Qb    = KV + FE;
    unsigned short* wT    = Qb + QE;
    float* attn  = (float*)(wT + WT);
    float* gpart = attn + (size_t)16384*16*3;
    float* coef  = gpart + 512*9;

    unsigned short* wT_v = wT;
    unsigned short* wT_t = wT_v + 786432;
    unsigned short* wT_a = wT_t + 524288;
    unsigned short* wT_q = wT_a + 1048576;
    unsigned short* wT_k = wT_q + 1048576;
    unsigned short* wT_vv= wT_k + 1048576;
    unsigned short* wT_o = wT_vv+ 1048576;
    unsigned short* in_v = KV;
    unsigned short* in_t = in_v + (size_t)16384*768;
    unsigned short* in_a = in_t + (size_t)16384*512;

    WtArgs wa;
    wa.src[0]=w_vision; wa.src[1]=w_text; wa.src[2]=w_audio; wa.src[3]=wq;
    wa.src[4]=wk; wa.src[5]=wv; wa.src[6]=wo;
    wa.dst[0]=wT_v; wa.dst[1]=wT_t; wa.dst[2]=wT_a; wa.dst[3]=wT_q;
    wa.dst[4]=wT_k; wa.dst[5]=wT_vv; wa.dst[6]=wT_o;
    wa.K[0]=768; wa.K[1]=512; wa.K[2]=1024; wa.K[3]=1024; wa.K[4]=1024;
    wa.K[5]=1024; wa.K[6]=1024;
    wa.cum[0]=0; wa.cum[1]=768; wa.cum[2]=1280; wa.cum[3]=2304; wa.cum[4]=3328;
    wa.cum[5]=4352; wa.cum[6]=5376; wa.cum[7]=6400;
    wtrans_all<<<6400, blk, 0, stream>>>(wa);

    CvtArgs ca;
    ca.s0 = vision; ca.s1 = text; ca.s2 = audio;
    ca.c0 = (long)16384*768/8;
    ca.c1 = ca.c0 + (long)16384*512/8;
    ca.ntot = ca.c1 + (long)16384*1024/8;
    cvt_all<<<4096, blk, 0, stream>>>(ca, in_v);

    gemm8p<0><<<256, 512, 131072, stream>>>(in_v, wT_v, b_vision, feats + 0*SD,
                                            1024, 768, 768, 16384, 0, 2048, 6144, 12);
    gemm8p<0><<<256, 512, 131072, stream>>>(in_t, wT_t, b_text,   feats + 1*SD,
                                            1024, 512, 512, 16384, 0, 2048, 6144, 8);
    gemm8p<0><<<256, 512, 131072, stream>>>(in_a, wT_a, b_audio,  feats + 2*SD,
                                            1024, 1024, 1024, 16384, 0, 2048, 6144, 16);
    gemm8p<0><<<256, 512, 131072, stream>>>(feats, wT_q, bq, Qb,
                                            1024, 1024, 1024, 2048, 6144, 16384, 0, 16);
    gemm8p<0><<<768, 512, 131072, stream>>>(feats, wT_k, bk, KV,
                                            1024, 1024, 1024, 49152, 0, 49152, 0, 16);
    scores_gram_kernel<<<4608, blk, 0, stream>>>(Qb, KV, temp, attn, feats, gpart);
    weights_kernel<<<1, 64, 0, stream>>>(gpart, temp, attnw, coef);
    gemm8p<0><<<768, 512, 131072, stream>>>(feats, wT_vv, bv, KV,
                                            1024, 1024, 1024, 49152, 0, 49152, 0, 16);
    fusemha_kernel<<<4096, blk, 0, stream>>>(KV, feats, attn, coef, Qb);
    gemm8p<1><<<256, 512, 131072, stream>>>(Qb, wT_o, bo, outp,
                                            1024, 1024, 1024, 16384, 0, 16384, 0, 16);
}

// Round 18
// 503.943 us; speedup vs baseline: 1.1634x; 1.0052x over previous
//
#include <hip/hip_runtime.h>

// GeometricModalityFusion on MI355X — round 17: combined-weight factorization
// (K/V/Q contract over d_m via precomputed W_m·w{k,v,q}; −13% GEMM work),
// r7 GEMM schedule unchanged. Fallback to r13 path if ws too small.
// f32 in/out; bf16 16x16x32 MFMA. B=8, S=2048, D=1024, H=16, M=3.

typedef __attribute__((ext_vector_type(8))) short bf16x8;
typedef __attribute__((ext_vector_type(4))) float f32x4;
typedef __attribute__((ext_vector_type(8))) unsigned short u16x8;

__device__ __forceinline__ float b2f(unsigned short u) {
    return __uint_as_float(((unsigned int)u) << 16);
}
__device__ __forceinline__ unsigned short f2b(float f) {
    unsigned int x = __float_as_uint(f);
    x += 0x7fffu + ((x >> 16) & 1u);   // RNE
    return (unsigned short)(x >> 16);
}
__device__ __forceinline__ void gl_lds16(const unsigned short* g, const unsigned short* l) {
    __builtin_amdgcn_global_load_lds(
        (const __attribute__((address_space(1))) unsigned int*)g,
        (__attribute__((address_space(3))) unsigned int*)(unsigned short*)l, 16, 0, 0);
}

// ---------------------------------------------------------------------------
// merged weight transpose+convert: 7 matrices f32 [K][1024] -> bf16 [1024][K]
// ---------------------------------------------------------------------------
struct WtArgs {
    const float* src[7];
    unsigned short* dst[7];
    int K[7];
    int cum[8];
};

__global__ __launch_bounds__(256) void wtrans_all(WtArgs a)
{
    __shared__ float t[32][33];
    const int bid = blockIdx.x;
    int m = 0;
    while (bid >= a.cum[m + 1]) ++m;
    const int local = bid - a.cum[m];
    const int K = a.K[m];
    const int kb = K >> 5;
    const int k0 = (local % kb) * 32;
    const int n0 = (local / kb) * 32;
    const float* in = a.src[m];
    unsigned short* out = a.dst[m];
    const int N = 1024;

    const int tx = threadIdx.x & 31, ty = threadIdx.x >> 5;
#pragma unroll
    for (int r = ty; r < 32; r += 8)
        t[r][tx] = in[(size_t)(k0 + r) * N + n0 + tx];
    __syncthreads();
#pragma unroll
    for (int r = ty; r < 32; r += 8)
        out[(size_t)(n0 + r) * K + k0 + tx] = f2b(t[tx][r]);
}

// merged f32 -> bf16 convert over 3 source segments into one contiguous dst
struct CvtArgs {
    const float* s0; const float* s1; const float* s2;
    long c0, c1, ntot;
};

__global__ __launch_bounds__(256) void cvt_all(CvtArgs a, unsigned short* __restrict__ dst)
{
    for (long i = (long)blockIdx.x * 256 + threadIdx.x; i < a.ntot; i += (long)gridDim.x * 256) {
        const float* src; long off;
        if (i < a.c0)      { src = a.s0; off = i; }
        else if (i < a.c1) { src = a.s1; off = i - a.c0; }
        else               { src = a.s2; off = i - a.c1; }
        const float4 v0 = *reinterpret_cast<const float4*>(src + off * 8);
        const float4 v1 = *reinterpret_cast<const float4*>(src + off * 8 + 4);
        u16x8 w;
        w[0]=f2b(v0.x); w[1]=f2b(v0.y); w[2]=f2b(v0.z); w[3]=f2b(v0.w);
        w[4]=f2b(v1.x); w[5]=f2b(v1.y); w[6]=f2b(v1.z); w[7]=f2b(v1.w);
        *reinterpret_cast<u16x8*>(dst + i * 8) = w;
    }
}

// ---------------------------------------------------------------------------
// 256x256 pipelined GEMM (r7 schedule): C[r][n]=sum_k A[amap(r)][k]*Bt[n][k]+bias[n]
// Bt rows may live in a wider matrix: bt_stride >= Kdim (element row pitch).
// bias may be nullptr (treated as 0). XCD swizzle only when gridDim.x%8==0.
// ---------------------------------------------------------------------------
template<int CF32>
__global__ __launch_bounds__(512, 2) void gemm8p(
    const unsigned short* __restrict__ A, const unsigned short* __restrict__ Bt,
    const float* __restrict__ bias, void* __restrict__ Cout,
    int Ndim, int Kdim, int bt_stride, int a_rpb, int a_bs, int c_rpb, int c_bs, int nt)
{
    extern __shared__ __align__(16) unsigned short lds[];   // A: [0,32768) B: [32768,65536) elems

    const int tid  = threadIdx.x;
    const int lane = tid & 63;
    const int w    = tid >> 6;
    const int wm = w >> 2, wn = w & 3;
    const int lr = lane & 15, lk = lane >> 4;

    const int ncol = Ndim >> 8;
    int wgid;
    if ((gridDim.x & 7) == 0) {
        const int cpx = gridDim.x >> 3;
        wgid = (blockIdx.x & 7) * cpx + (blockIdx.x >> 3);
    } else {
        wgid = blockIdx.x;
    }
    const int m0 = (wgid / ncol) << 8;
    const int n0 = (wgid % ncol) << 8;

    const int srow  = tid >> 3;
    const int gslot = (tid & 7) ^ (srow & 7);
    const int gr0   = m0 + srow;
    const size_t asrc0 = ((size_t)((gr0 / a_rpb) * a_bs + (gr0 % a_rpb))) * Kdim + gslot * 8;
    const size_t bsrc0 = ((size_t)(n0 + srow)) * bt_stride + gslot * 8;
    const size_t arstep = (size_t)64 * Kdim;
    const size_t brstep = (size_t)64 * bt_stride;
    const int sdst = (w << 9);   // wave-uniform LDS base (HW adds lane*16B)

#define STAGE_A(doff, j, tt) gl_lds16(A  + asrc0 + (size_t)(j)*arstep + (size_t)(tt)*64, \
                                      lds + (doff) + (j)*4096 + sdst)
#define STAGE_B(doff, j, tt) gl_lds16(Bt + bsrc0 + (size_t)(j)*brstep + (size_t)(tt)*64, \
                                      lds + 32768 + (doff) + (j)*4096 + sdst)

    const int sel0 = ((lk)     ^ (lr & 7)) * 8;
    const int sel1 = ((lk + 4) ^ (lr & 7)) * 8;
    const int arow = (wm * 128 + lr) * 64;
    const int brow = (wn * 64  + lr) * 64;

#define LDV(off) (*reinterpret_cast<const bf16x8*>(lds + (off)))

    f32x4 acc[8][4];
    const f32x4 zero = {0.f, 0.f, 0.f, 0.f};
#pragma unroll
    for (int a = 0; a < 8; ++a)
#pragma unroll
        for (int b = 0; b < 4; ++b) acc[a][b] = zero;

    bf16x8 af[4][2], bfA[2][2], bfB[2][2];

#define READ_AF(base, roff) \
    _Pragma("unroll") \
    for (int a = 0; a < 4; ++a) { \
        af[a][0] = LDV((base) + arow + ((roff) + a) * 1024 + sel0); \
        af[a][1] = LDV((base) + arow + ((roff) + a) * 1024 + sel1); \
    }
#define READ_BFA(base) \
    _Pragma("unroll") \
    for (int b = 0; b < 2; ++b) { \
        bfA[b][0] = LDV(32768 + (base) + brow + b * 1024 + sel0); \
        bfA[b][1] = LDV(32768 + (base) + brow + b * 1024 + sel1); \
    }
#define READ_BFB(base) \
    _Pragma("unroll") \
    for (int b = 0; b < 2; ++b) { \
        bfB[b][0] = LDV(32768 + (base) + brow + (2 + b) * 1024 + sel0); \
        bfB[b][1] = LDV(32768 + (base) + brow + (2 + b) * 1024 + sel1); \
    }

#define MFMA_Q(RA, CB, BF) \
    _Pragma("unroll") \
    for (int a = 0; a < 4; ++a) { \
        _Pragma("unroll") \
        for (int b = 0; b < 2; ++b) { \
            acc[RA+a][CB+b] = __builtin_amdgcn_mfma_f32_16x16x32_bf16(af[a][0], BF[b][0], acc[RA+a][CB+b], 0, 0, 0); \
            acc[RA+a][CB+b] = __builtin_amdgcn_mfma_f32_16x16x32_bf16(af[a][1], BF[b][1], acc[RA+a][CB+b], 0, 0, 0); \
        } \
    }

    // prologue: stage tile 0 into buf 0; drain; barrier; pre-read R0
#pragma unroll
    for (int j = 0; j < 4; ++j) STAGE_A(0, j, 0);
#pragma unroll
    for (int j = 0; j < 4; ++j) STAGE_B(0, j, 0);
    asm volatile("s_waitcnt vmcnt(0)" ::: "memory");
    __builtin_amdgcn_s_barrier();
    READ_AF(0, 0);
    READ_BFA(0);

    for (int t = 0; t < nt; ++t) {
        const int cur = (t & 1) << 14;
        const int nb  = ((t + 1) & 1) << 14;
        const bool pf = (t + 1) < nt;

        // ph0: MFMA Q0 ; read bfB ; stage A(t+1)
        __builtin_amdgcn_s_setprio(1);
        MFMA_Q(0, 0, bfA);
        __builtin_amdgcn_s_setprio(0);
        READ_BFB(cur);
        if (pf) {
            STAGE_A(nb, 0, t+1); STAGE_A(nb, 1, t+1);
            STAGE_A(nb, 2, t+1); STAGE_A(nb, 3, t+1);
        }

        // ph1: MFMA Q1 ; read af47 ; stage B(t+1)
        __builtin_amdgcn_s_setprio(1);
        MFMA_Q(0, 2, bfB);
        __builtin_amdgcn_s_setprio(0);
        READ_AF(cur, 4);
        if (pf) {
            STAGE_B(nb, 0, t+1); STAGE_B(nb, 1, t+1);
            STAGE_B(nb, 2, t+1); STAGE_B(nb, 3, t+1);
        }

        // ph2+3: MFMA Q2, Q3
        __builtin_amdgcn_s_setprio(1);
        MFMA_Q(4, 2, bfB);
        MFMA_Q(4, 0, bfA);
        __builtin_amdgcn_s_setprio(0);

        // boundary
        asm volatile("s_waitcnt vmcnt(0)" ::: "memory");
        __builtin_amdgcn_s_barrier();
        if (pf) {
            READ_AF(nb, 0);
            READ_BFA(nb);
        }
    }

    // epilogue: C/D layout col=lane&15, row=(lane>>4)*4+r; bias hoisted
    const int grow0 = m0 + wm * 128;
    const int crow0 = (grow0 / c_rpb) * c_bs + (grow0 % c_rpb);
    float bv[4];
#pragma unroll
    for (int b = 0; b < 4; ++b)
        bv[b] = bias ? bias[n0 + wn * 64 + b * 16 + lr] : 0.f;
#pragma unroll
    for (int a = 0; a < 8; ++a) {
#pragma unroll
        for (int b = 0; b < 4; ++b) {
            const int gcol = n0 + wn * 64 + b * 16 + lr;
#pragma unroll
            for (int r = 0; r < 4; ++r) {
                const int crow = crow0 + a * 16 + lk * 4 + r;
                if constexpr (CF32) {
                    ((float*)Cout)[(size_t)crow * Ndim + gcol] = acc[a][b][r] + bv[b];
                } else {
                    ((unsigned short*)Cout)[(size_t)crow * Ndim + gcol] = f2b(acc[a][b][r] + bv[b]);
                }
            }
        }
    }
#undef STAGE_A
#undef STAGE_B
#undef LDV
#undef READ_AF
#undef READ_BFA
#undef READ_BFB
#undef MFMA_Q
}

// ---------------------------------------------------------------------------
// Combined scores (blocks 0..4095) + gram partials (blocks 4096..4607).
// ---------------------------------------------------------------------------
__global__ __launch_bounds__(256) void scores_gram_kernel(
    const unsigned short* __restrict__ Q, const unsigned short* __restrict__ Kb,
    const float* __restrict__ temp, float* __restrict__ attn,
    const unsigned short* __restrict__ feats, float* __restrict__ gpart)
{
    __shared__ float red[4][9];
    if (blockIdx.x < 4096) {
        const int lane = threadIdx.x & 63;
        const int w  = blockIdx.x * 4 + (threadIdx.x >> 6);
        const int b  = w >> 11;
        const int s  = w & 2047;
        const float t = fabsf(temp[0]);
        const float inv = 1.f / (8.f * t);
        const size_t qbase = (((size_t)w) << 10) + lane * 8;
        const u16x8 qv0 = *reinterpret_cast<const u16x8*>(Q + qbase);
        const u16x8 qv1 = *reinterpret_cast<const u16x8*>(Q + qbase + 512);
        float sc0[3], sc1[3];
#pragma unroll
        for (int m = 0; m < 3; ++m) {
            const size_t koff = ((((size_t)(b*3 + m) << 11) + s) << 10) + lane * 8;
            const u16x8 kv0 = *reinterpret_cast<const u16x8*>(Kb + koff);
            const u16x8 kv1 = *reinterpret_cast<const u16x8*>(Kb + koff + 512);
            float p0 = 0.f, p1 = 0.f;
#pragma unroll
            for (int j = 0; j < 8; ++j) {
                p0 = fmaf(b2f(qv0[j]), b2f(kv0[j]), p0);
                p1 = fmaf(b2f(qv1[j]), b2f(kv1[j]), p1);
            }
            p0 += __shfl_xor(p0, 1); p0 += __shfl_xor(p0, 2); p0 += __shfl_xor(p0, 4);
            p1 += __shfl_xor(p1, 1); p1 += __shfl_xor(p1, 2); p1 += __shfl_xor(p1, 4);
            sc0[m] = p0 * inv;
            sc1[m] = p1 * inv;
        }
        const float mx0 = fmaxf(sc0[0], fmaxf(sc0[1], sc0[2]));
        const float a0 = expf(sc0[0]-mx0), a1 = expf(sc0[1]-mx0), a2 = expf(sc0[2]-mx0);
        const float is0 = 1.f / (a0 + a1 + a2);
        const float mx1 = fmaxf(sc1[0], fmaxf(sc1[1], sc1[2]));
        const float c0 = expf(sc1[0]-mx1), c1 = expf(sc1[1]-mx1), c2 = expf(sc1[2]-mx1);
        const float is1 = 1.f / (c0 + c1 + c2);
        if ((lane & 7) == 0) {
            const int h0 = lane >> 3;
            const size_t b0 = ((size_t)w * 16 + h0) * 3;
            const size_t b1 = ((size_t)w * 16 + 8 + h0) * 3;
            attn[b0+0] = a0 * is0; attn[b0+1] = a1 * is0; attn[b0+2] = a2 * is0;
            attn[b1+0] = c0 * is1; attn[b1+1] = c1 * is1; attn[b1+2] = c2 * is1;
        }
        return;
    }

    const int gb    = blockIdx.x - 4096;
    const int b     = gb >> 6;
    const int chunk = gb & 63;
    const int wave  = threadIdx.x >> 6;
    const int lane  = threadIdx.x & 63;
    float acc[9];
#pragma unroll
    for (int i = 0; i < 9; ++i) acc[i] = 0.f;
    const int s_base = chunk * 32 + wave * 8;
    const size_t bbase = ((size_t)(b*3)) << 21;
    for (int ti = 0; ti < 8; ++ti) {
        const size_t rowoff = ((size_t)(s_base + ti)) << 10;
        float g[6] = {0.f,0.f,0.f,0.f,0.f,0.f};
#pragma unroll
        for (int half = 0; half < 2; ++half) {
            const int d = (half << 9) + (lane << 3);
            u16x8 v0 = *(const u16x8*)(feats + bbase + rowoff + d);
            u16x8 v1 = *(const u16x8*)(feats + bbase + ((size_t)1<<21) + rowoff + d);
            u16x8 v2 = *(const u16x8*)(feats + bbase + ((size_t)2<<21) + rowoff + d);
#pragma unroll
            for (int j = 0; j < 8; ++j) {
                float x0 = b2f(v0[j]), x1 = b2f(v1[j]), x2 = b2f(v2[j]);
                g[0] = fmaf(x0,x0,g[0]); g[1] = fmaf(x0,x1,g[1]); g[2] = fmaf(x0,x2,g[2]);
                g[3] = fmaf(x1,x1,g[3]); g[4] = fmaf(x1,x2,g[4]); g[5] = fmaf(x2,x2,g[5]);
            }
        }
#pragma unroll
        for (int i = 0; i < 6; ++i) {
#pragma unroll
            for (int o = 32; o > 0; o >>= 1) g[i] += __shfl_xor(g[i], o);
        }
        const float n0 = fmaxf(sqrtf(g[0]), 1e-12f);
        const float n1 = fmaxf(sqrtf(g[3]), 1e-12f);
        const float n2 = fmaxf(sqrtf(g[5]), 1e-12f);
        acc[0]+=g[0]; acc[1]+=g[1]; acc[2]+=g[2]; acc[3]+=g[3]; acc[4]+=g[4]; acc[5]+=g[5];
        acc[6]+=g[1]/(n0*n1); acc[7]+=g[2]/(n0*n2); acc[8]+=g[4]/(n1*n2);
    }
    if (lane == 0) {
#pragma unroll
        for (int i = 0; i < 9; ++i) red[wave][i] = acc[i];
    }
    __syncthreads();
    if (threadIdx.x == 0) {
#pragma unroll
        for (int i = 0; i < 9; ++i)
            gpart[gb * 9 + i] = red[0][i] + red[1][i] + red[2][i] + red[3][i];
    }
}

// per-batch scalar weights: angular (aw) + cayley (cw) + fusion softmax (fw)
__global__ void weights_kernel(const float* __restrict__ gpart,
                               const float* __restrict__ temp,
                               const float* __restrict__ attnw,
                               float* __restrict__ coef)
{
    const int b = threadIdx.x;
    if (b >= 8) return;
    const float t = fabsf(temp[0]);

    float a0 = attnw[0], a1 = attnw[1], a2 = attnw[2];
    float amx = fmaxf(a0, fmaxf(a1, a2));
    float fe0 = expf(a0-amx), fe1 = expf(a1-amx), fe2 = expf(a2-amx);
    float fs = fe0 + fe1 + fe2;
    float fw0 = fe0/fs, fw1 = fe1/fs, fw2 = fe2/fs;

    float g[9];
#pragma unroll
    for (int i = 0; i < 9; ++i) {
        float ssum = 0.f;
        for (int c = 0; c < 64; ++c) ssum += gpart[(b*64 + c)*9 + i];
        g[i] = ssum;
    }
    const float G[3][3] = {{g[0],g[1],g[2]},{g[1],g[3],g[4]},{g[2],g[4],g[5]}};

    const float c01 = g[6] / 2048.f, c02 = g[7] / 2048.f, c12 = g[8] / 2048.f;
    const float lo = -1.f + 1e-7f, hi = 1.f - 1e-7f;
    const float ang01 = acosf(fminf(fmaxf(c01, lo), hi));
    const float ang02 = acosf(fminf(fmaxf(c02, lo), hi));
    const float ang12 = acosf(fminf(fmaxf(c12, lo), hi));
    const float e01 = expf(-ang01/t), e02 = expf(-ang02/t), e12 = expf(-ang12/t);
    const float l0 = e01*(-0.75f) + e02*(0.75f);
    const float l1 = e01*(1.0f)   + e12*(0.75f);
    const float l2 = e02*(1.0f)   + e12*(-0.75f);
    const float lm = fmaxf(l0, fmaxf(l1, l2));
    const float ae0 = expf(l0-lm), ae1 = expf(l1-lm), ae2 = expf(l2-lm);
    const float as = ae0 + ae1 + ae2;
    const float aw[3] = {ae0/as, ae1/as, ae2/as};

    float vol[3];
#pragma unroll
    for (int i = 0; i < 3; ++i) {
        float Ac[3][3] = {{0.f,0.f,0.f},{0.f,0.f,0.f},{0.f,0.f,0.f}};
        Ac[0][i] = 1.f;
        Ac[1][i] = 0.70710678f; Ac[1][(i+1)%3] += 0.70710678f;
        Ac[2][(i+2)%3] = 1.f;
        float Gi[3][3];
        for (int p = 0; p < 3; ++p)
            for (int q = 0; q < 3; ++q) {
                float ssum = 0.f;
                for (int k = 0; k < 3; ++k)
                    for (int l = 0; l < 3; ++l)
                        ssum += Ac[p][k] * G[k][l] * Ac[q][l];
                Gi[p][q] = ssum;
            }
        float ds = 0.f;
        for (int p = 0; p < 3; ++p)
            for (int q = 0; q < 3; ++q)
                ds += Gi[p][p] + Gi[q][q] - 2.f*Gi[p][q];
        vol[i] = ds / 9.f;
    }
    const float lv0 = vol[0]/t, lv1 = vol[1]/t, lv2 = vol[2]/t;
    const float vm = fmaxf(lv0, fmaxf(lv1, lv2));
    const float ce0 = expf(lv0-vm), ce1 = expf(lv1-vm), ce2 = expf(lv2-vm);
    const float cs = ce0 + ce1 + ce2;
    const float cw[3] = {ce0/cs, ce1/cs, ce2/cs};

    coef[b*4+0] = fw1*aw[0] + fw2*cw[0];
    coef[b*4+1] = fw1*aw[1] + fw2*cw[1];
    coef[b*4+2] = fw1*aw[2] + fw2*cw[2];
    coef[b*4+3] = fw0;
}

// ---------------------------------------------------------------------------
// Merged mha+fuse.
// ---------------------------------------------------------------------------
__global__ __launch_bounds__(256) void fusemha_kernel(
    const unsigned short* __restrict__ Vb, const unsigned short* __restrict__ feats,
    const float* __restrict__ attn, const float* __restrict__ coef,
    unsigned short* __restrict__ fused)
{
    const int lane = threadIdx.x & 63;
    const int w  = blockIdx.x * 4 + (threadIdx.x >> 6);
    const int b  = w >> 11;
    const int s  = w & 2047;
    const int h0 = lane >> 3;
    const float fw0 = coef[b*4+3];
    const float c0 = coef[b*4+0], c1 = coef[b*4+1], c2 = coef[b*4+2];
    const size_t ab0 = ((size_t)w * 16 + h0) * 3;
    const size_t ab1 = ((size_t)w * 16 + 8 + h0) * 3;
    const float a00 = fw0*attn[ab0+0], a01 = fw0*attn[ab0+1], a02 = fw0*attn[ab0+2];
    const float a10 = fw0*attn[ab1+0], a11 = fw0*attn[ab1+1], a12 = fw0*attn[ab1+2];
    const size_t base = ((((size_t)(b*3) << 11) + s) << 10) + lane * 8;
    const size_t ms = (size_t)1 << 21;
    const u16x8 v00 = *reinterpret_cast<const u16x8*>(Vb + base);
    const u16x8 v01 = *reinterpret_cast<const u16x8*>(Vb + base + ms);
    const u16x8 v02 = *reinterpret_cast<const u16x8*>(Vb + base + 2*ms);
    const u16x8 v10 = *reinterpret_cast<const u16x8*>(Vb + base + 512);
    const u16x8 v11 = *reinterpret_cast<const u16x8*>(Vb + base + ms + 512);
    const u16x8 v12 = *reinterpret_cast<const u16x8*>(Vb + base + 2*ms + 512);
    const u16x8 f00 = *reinterpret_cast<const u16x8*>(feats + base);
    const u16x8 f01 = *reinterpret_cast<const u16x8*>(feats + base + ms);
    const u16x8 f02 = *reinterpret_cast<const u16x8*>(feats + base + 2*ms);
    const u16x8 f10 = *reinterpret_cast<const u16x8*>(feats + base + 512);
    const u16x8 f11 = *reinterpret_cast<const u16x8*>(feats + base + ms + 512);
    const u16x8 f12 = *reinterpret_cast<const u16x8*>(feats + base + 2*ms + 512);
    u16x8 o0, o1;
#pragma unroll
    for (int j = 0; j < 8; ++j) {
        o0[j] = f2b(a00*b2f(v00[j]) + a01*b2f(v01[j]) + a02*b2f(v02[j])
                  + c0*b2f(f00[j]) + c1*b2f(f01[j]) + c2*b2f(f02[j]));
        o1[j] = f2b(a10*b2f(v10[j]) + a11*b2f(v11[j]) + a12*b2f(v12[j])
                  + c0*b2f(f10[j]) + c1*b2f(f11[j]) + c2*b2f(f12[j]));
    }
    const size_t qoff = (((size_t)w) << 10) + lane * 8;
    *reinterpret_cast<u16x8*>(fused + qoff) = o0;
    *reinterpret_cast<u16x8*>(fused + qoff + 512) = o1;
}

// ---------------------------------------------------------------------------
extern "C" void kernel_launch(void* const* d_in, const int* in_sizes, int n_in,
                              void* d_out, int out_size, void* d_ws, size_t ws_size,
                              hipStream_t stream) {
    (void)in_sizes; (void)n_in; (void)out_size;
    const float* vision   = (const float*)d_in[0];
    const float* w_vision = (const float*)d_in[1];
    const float* b_vision = (const float*)d_in[2];
    const float* text     = (const float*)d_in[3];
    const float* w_text   = (const float*)d_in[4];
    const float* b_text   = (const float*)d_in[5];
    const float* audio    = (const float*)d_in[6];
    const float* w_audio  = (const float*)d_in[7];
    const float* b_audio  = (const float*)d_in[8];
    const float* wq = (const float*)d_in[9];
    const float* bq = (const float*)d_in[10];
    const float* wk = (const float*)d_in[11];
    const float* bk = (const float*)d_in[12];
    const float* wv = (const float*)d_in[13];
    const float* bv = (const float*)d_in[14];
    const float* wo = (const float*)d_in[15];
    const float* bo = (const float*)d_in[16];
    const float* temp  = (const float*)d_in[17];
    const float* attnw = (const float*)d_in[18];

    const size_t SD = (size_t)2048 * 1024;     // 1<<21
    const size_t FE = 24 * SD;                 // B*M*S*D
    const size_t QE = 8 * SD;                  // B*S*D
    const size_t WT = 6553600;                 // transposed bf16 weights
    const size_t INC = (size_t)16384 * 2304;   // concatenated bf16 inputs
    const size_t WRAW = (size_t)2304 * 1024;   // stacked raw bf16 weights
    const size_t WCAT = (size_t)3072 * 2304;   // combined weights

    const size_t small_f32 = ((size_t)16384*16*3 + 512*9 + 32) * 4;
    const size_t need_new = (FE + FE + QE + INC + WT + WRAW + WCAT) * 2 + small_f32;
    const size_t need_old = (2*FE + QE + WT) * 2 + small_f32;
    if (ws_size < need_old) return;
    const bool big = (ws_size >= need_new);

    (void)hipFuncSetAttribute((const void*)gemm8p<0>,
                              hipFuncAttributeMaxDynamicSharedMemorySize, 131072);
    (void)hipFuncSetAttribute((const void*)gemm8p<1>,
                              hipFuncAttributeMaxDynamicSharedMemorySize, 131072);

    dim3 blk(256);
    float* outp = (float*)d_out;

    if (big) {
        unsigned short* feats = (unsigned short*)d_ws;
        unsigned short* KV    = feats + FE;
        unsigned short* Qb    = KV + FE;
        unsigned short* inc   = Qb + QE;          // [in_v | in_t | in_a]
        unsigned short* wT    = inc + INC;        // [v t a o k vv q]
        unsigned short* wraw  = wT + WT;          // [Wv ; Wt ; Wa] bf16 raw
        unsigned short* wcat  = wraw + WRAW;      // [k;v;q]x[vis|txt|aud] combined
        float* attn  = (float*)(wcat + WCAT);
        float* gpart = attn + (size_t)16384*16*3;
        float* coef  = gpart + 512*9;

        unsigned short* wT_v = wT;
        unsigned short* wT_t = wT_v + 786432;
        unsigned short* wT_a = wT_t + 524288;
        unsigned short* wT_o = wT_a + 1048576;
        unsigned short* wT_k = wT_o + 1048576;    // k,vv,q contiguous = A_cat
        unsigned short* in_v = inc;
        unsigned short* in_t = in_v + (size_t)16384*768;
        unsigned short* in_a = in_t + (size_t)16384*512;

        // 1) weight transpose+convert (order: v t a o k vv q)
        WtArgs wa;
        wa.src[0]=w_vision; wa.src[1]=w_text; wa.src[2]=w_audio; wa.src[3]=wo;
        wa.src[4]=wk; wa.src[5]=wv; wa.src[6]=wq;
        wa.dst[0]=wT_v; wa.dst[1]=wT_t; wa.dst[2]=wT_a; wa.dst[3]=wT_o;
        wa.dst[4]=wT_k; wa.dst[5]=wT_k+1048576; wa.dst[6]=wT_k+2097152;
        wa.K[0]=768; wa.K[1]=512; wa.K[2]=1024; wa.K[3]=1024; wa.K[4]=1024;
        wa.K[5]=1024; wa.K[6]=1024;
        wa.cum[0]=0; wa.cum[1]=768; wa.cum[2]=1280; wa.cum[3]=2304; wa.cum[4]=3328;
        wa.cum[5]=4352; wa.cum[6]=5376; wa.cum[7]=6400;
        wtrans_all<<<6400, blk, 0, stream>>>(wa);

        // 2) inputs f32->bf16 ; 3) raw weights f32->bf16 (stacked [2304][1024])
        CvtArgs ci;
        ci.s0 = vision; ci.s1 = text; ci.s2 = audio;
        ci.c0 = (long)16384*768/8;
        ci.c1 = ci.c0 + (long)16384*512/8;
        ci.ntot = ci.c1 + (long)16384*1024/8;
        cvt_all<<<4096, blk, 0, stream>>>(ci, in_v);
        CvtArgs cw2;
        cw2.s0 = w_vision; cw2.s1 = w_text; cw2.s2 = w_audio;
        cw2.c0 = (long)768*1024/8;
        cw2.c1 = cw2.c0 + (long)512*1024/8;
        cw2.ntot = cw2.c1 + (long)1024*1024/8;
        cvt_all<<<1152, blk, 0, stream>>>(cw2, wraw);

        // 4) combined weights: wcat[3072][2304] = [wkT;wvT;wqT] x wraw^T
        gemm8p<0><<<108, 512, 131072, stream>>>(wT_k, wraw, nullptr, wcat,
                                                2304, 1024, 1024, 3072, 0, 3072, 0, 16);
        // 5) projections -> feats (row scatter 2048/6144)
        gemm8p<0><<<256, 512, 131072, stream>>>(in_v, wT_v, b_vision, feats + 0*SD,
                                                1024, 768, 768, 16384, 0, 2048, 6144, 12);
        gemm8p<0><<<256, 512, 131072, stream>>>(in_t, wT_t, b_text,   feats + 1*SD,
                                                1024, 512, 512, 16384, 0, 2048, 6144, 8);
        gemm8p<0><<<256, 512, 131072, stream>>>(in_a, wT_a, b_audio,  feats + 2*SD,
                                                1024, 1024, 1024, 16384, 0, 2048, 6144, 16);
        // 6) Q = in_v @ (Wv.wq) : q-section rows (2048..3071), vision cols
        gemm8p<0><<<256, 512, 131072, stream>>>(in_v, wcat + (size_t)2048*2304, bq, Qb,
                                                1024, 768, 2304, 16384, 0, 16384, 0, 12);
        // 7) K_m = in_m @ (Wm.wk) : k-section rows (0..1023)
        gemm8p<0><<<256, 512, 131072, stream>>>(in_v, wcat + 0,    bk, KV + 0*SD,
                                                1024, 768, 2304, 16384, 0, 2048, 6144, 12);
        gemm8p<0><<<256, 512, 131072, stream>>>(in_t, wcat + 768,  bk, KV + 1*SD,
                                                1024, 512, 2304, 16384, 0, 2048, 6144, 8);
        gemm8p<0><<<256, 512, 131072, stream>>>(in_a, wcat + 1280, bk, KV + 2*SD,
                                                1024, 1024, 2304, 16384, 0, 2048, 6144, 16);
        // 8) scores+gram ; 9) per-batch weights
        scores_gram_kernel<<<4608, blk, 0, stream>>>(Qb, KV, temp, attn, feats, gpart);
        weights_kernel<<<1, 64, 0, stream>>>(gpart, temp, attnw, coef);
        // 10) V_m = in_m @ (Wm.wv) : v-section rows (1024..2047)
        gemm8p<0><<<256, 512, 131072, stream>>>(in_v, wcat + (size_t)1024*2304,        bv, KV + 0*SD,
                                                1024, 768, 2304, 16384, 0, 2048, 6144, 12);
        gemm8p<0><<<256, 512, 131072, stream>>>(in_t, wcat + (size_t)1024*2304 + 768,  bv, KV + 1*SD,
                                                1024, 512, 2304, 16384, 0, 2048, 6144, 8);
        gemm8p<0><<<256, 512, 131072, stream>>>(in_a, wcat + (size_t)1024*2304 + 1280, bv, KV + 2*SD,
                                                1024, 1024, 2304, 16384, 0, 2048, 6144, 16);
        // 11) merged mha+fusion -> Qb ; 12) output projection
        fusemha_kernel<<<4096, blk, 0, stream>>>(KV, feats, attn, coef, Qb);
        gemm8p<1><<<256, 512, 131072, stream>>>(Qb, wT_o, bo, outp,
                                                1024, 1024, 1024, 16384, 0, 16384, 0, 16);
        return;
    }

    // ---------------- fallback: r13 layout/sequence ----------------
    unsigned short* feats = (unsigned short*)d_ws;
    unsigned short* KV    = feats + FE;
    unsigned short* Qb    = KV + FE;
    unsigned short* wT    = Qb + QE;
    float* attn  = (float*)(wT + WT);
    float* gpart = attn + (size_t)16384*16*3;
    float* coef  = gpart + 512*9;

    unsigned short* wT_v = wT;
    unsigned short* wT_t = wT_v + 786432;
    unsigned short* wT_a = wT_t + 524288;
    unsigned short* wT_q = wT_a + 1048576;
    unsigned short* wT_k = wT_q + 1048576;
    unsigned short* wT_vv= wT_k + 1048576;
    unsigned short* wT_o = wT_vv+ 1048576;
    unsigned short* in_v = KV;
    unsigned short* in_t = in_v + (size_t)16384*768;
    unsigned short* in_a = in_t + (size_t)16384*512;

    WtArgs wa;
    wa.src[0]=w_vision; wa.src[1]=w_text; wa.src[2]=w_audio; wa.src[3]=wq;
    wa.src[4]=wk; wa.src[5]=wv; wa.src[6]=wo;
    wa.dst[0]=wT_v; wa.dst[1]=wT_t; wa.dst[2]=wT_a; wa.dst[3]=wT_q;
    wa.dst[4]=wT_k; wa.dst[5]=wT_vv; wa.dst[6]=wT_o;
    wa.K[0]=768; wa.K[1]=512; wa.K[2]=1024; wa.K[3]=1024; wa.K[4]=1024;
    wa.K[5]=1024; wa.K[6]=1024;
    wa.cum[0]=0; wa.cum[1]=768; wa.cum[2]=1280; wa.cum[3]=2304; wa.cum[4]=3328;
    wa.cum[5]=4352; wa.cum[6]=5376; wa.cum[7]=6400;
    wtrans_all<<<6400, blk, 0, stream>>>(wa);

    CvtArgs ca;
    ca.s0 = vision; ca.s1 = text; ca.s2 = audio;
    ca.c0 = (long)16384*768/8;
    ca.c1 = ca.c0 + (long)16384*512/8;
    ca.ntot = ca.c1 + (long)16384*1024/8;
    cvt_all<<<4096, blk, 0, stream>>>(ca, in_v);

    gemm8p<0><<<256, 512, 131072, stream>>>(in_v, wT_v, b_vision, feats + 0*SD,
                                            1024, 768, 768, 16384, 0, 2048, 6144, 12);
    gemm8p<0><<<256, 512, 131072, stream>>>(in_t, wT_t, b_text,   feats + 1*SD,
                                            1024, 512, 512, 16384, 0, 2048, 6144, 8);
    gemm8p<0><<<256, 512, 131072, stream>>>(in_a, wT_a, b_audio,  feats + 2*SD,
                                            1024, 1024, 1024, 16384, 0, 2048, 6144, 16);
    gemm8p<0><<<256, 512, 131072, stream>>>(feats, wT_q, bq, Qb,
                                            1024, 1024, 1024, 2048, 6144, 16384, 0, 16);
    gemm8p<0><<<768, 512, 131072, stream>>>(feats, wT_k, bk, KV,
                                            1024, 1024, 1024, 49152, 0, 49152, 0, 16);
    scores_gram_kernel<<<4608, blk, 0, stream>>>(Qb, KV, temp, attn, feats, gpart);
    weights_kernel<<<1, 64, 0, stream>>>(gpart, temp, attnw, coef);
    gemm8p<0><<<768, 512, 131072, stream>>>(feats, wT_vv, bv, KV,
                                            1024, 1024, 1024, 49152, 0, 49152, 0, 16);
    fusemha_kernel<<<4096, blk, 0, stream>>>(KV, feats, attn, coef, Qb);
    gemm8p<1><<<256, 512, 131072, stream>>>(Qb, wT_o, bo, outp,
                                            1024, 1024, 1024, 16384, 0, 16384, 0, 16);
}